// Round 11
// baseline (1449.193 us; speedup 1.0000x reference)
//
#include <hip/hip_runtime.h>
#include <hip/hip_bf16.h>
#include <cstdint>

typedef float f32x4 __attribute__((ext_vector_type(4)));
typedef short bf16x8 __attribute__((ext_vector_type(8)));

__device__ __forceinline__ unsigned short f32_to_bf16_rne(float f) {
  unsigned int u = __float_as_uint(f);
  return (unsigned short)((u + 0x7FFFu + ((u >> 16) & 1u)) >> 16);
}

#define GLOAD_LDS16(gptr, lptr)                                                             \
  __builtin_amdgcn_global_load_lds((const __attribute__((address_space(1))) unsigned int*)(gptr), \
                                   (__attribute__((address_space(3))) unsigned int*)(lptr), 16, 0, 0)

// ---------------- fused f32 -> bf16 for all 5 operands (8 elems / thread) ----------------
__global__ __launch_bounds__(256) void cvt_all(const float* __restrict__ wv,
                                               const float* __restrict__ q,
                                               const float* __restrict__ v,
                                               const float* __restrict__ wq,
                                               const float* __restrict__ wo,
                                               unsigned short* __restrict__ wvb,
                                               unsigned short* __restrict__ qb,
                                               unsigned short* __restrict__ vb,
                                               unsigned short* __restrict__ wqb,
                                               unsigned short* __restrict__ wob) {
  int i = blockIdx.x * 256 + threadIdx.x;  // chunk of 8 floats
  const float* src;
  unsigned short* dst;
  int off;
  if (i < 4194304)      { src = wv; dst = wvb; off = i; }
  else if (i < 4456448) { src = q;  dst = qb;  off = i - 4194304; }
  else if (i < 4718592) { src = v;  dst = vb;  off = i - 4456448; }
  else if (i < 4849664) { src = wq; dst = wqb; off = i - 4718592; }
  else                  { src = wo; dst = wob; off = i - 4849664; }
  const float4* s = (const float4*)src;
  float4 a = s[2 * off], b = s[2 * off + 1];
  uint4 o;
  o.x = (unsigned)f32_to_bf16_rne(a.x) | ((unsigned)f32_to_bf16_rne(a.y) << 16);
  o.y = (unsigned)f32_to_bf16_rne(a.z) | ((unsigned)f32_to_bf16_rne(a.w) << 16);
  o.z = (unsigned)f32_to_bf16_rne(b.x) | ((unsigned)f32_to_bf16_rne(b.y) << 16);
  o.w = (unsigned)f32_to_bf16_rne(b.z) | ((unsigned)f32_to_bf16_rne(b.w) << 16);
  ((uint4*)dst)[off] = o;
}

// ---------------- fuzzy membership + softmax: LDS-staged rules, one head per block --------
__global__ __launch_bounds__(256) void fuzzy2_k(const float* __restrict__ qf,
                                                const float* __restrict__ rk,
                                                const float* __restrict__ rw,
                                                float* __restrict__ attn) {
  __shared__ float lk[32][65];
  __shared__ float lc[32][65];
  const int tid = threadIdx.x;
  const int h = blockIdx.y;
  const int mbase = blockIdx.x * 128;

  for (int idx = tid; idx < 2048; idx += 256) {
    int r = idx >> 6, d = idx & 63;
    lk[r][d] = rk[(size_t)(h * 32 + r) * 64 + d];
    float w = rw[(size_t)(h * 32 + r) * 64 + d];
    lc[r][d] = 0.0078125f / (w * w);
  }
  __syncthreads();

  const int g = tid >> 5;
  const int r = tid & 31;
#pragma unroll 1
  for (int it = 0; it < 16; ++it) {
    int m = mbase + it * 8 + g;
    const float* qrow = qf + (size_t)m * 1024 + h * 64;
    float acc = 0.f;
#pragma unroll
    for (int d0 = 0; d0 < 64; d0 += 4) {
      float4 q4 = *(const float4*)(qrow + d0);
      const float* qp = (const float*)&q4;
#pragma unroll
      for (int j = 0; j < 4; ++j) {
        float diff = qp[j] - lk[r][d0 + j];
        acc += lc[r][d0 + j] * diff * diff;
      }
    }
    float z = -acc;
    float mx = z;
#pragma unroll
    for (int mask = 16; mask >= 1; mask >>= 1) mx = fmaxf(mx, __shfl_xor(mx, mask));
    float e = __expf(z - mx);
    float s = e;
#pragma unroll
    for (int mask = 16; mask >= 1; mask >>= 1) s += __shfl_xor(s, mask);
    attn[(size_t)m * 512 + h * 32 + r] = e / s;
  }
}

// ---------------- small bf16 GEMM (64x64 tile, 512 blocks, ~8/CU): C = (A@W^T+b)*scale ----
__global__ __launch_bounds__(256) void gemm_bt64(const unsigned short* __restrict__ A,
                                                 const unsigned short* __restrict__ W,
                                                 const float* __restrict__ bias, float scale,
                                                 int M, int N, int K, float* __restrict__ Cf) {
  constexpr int BK = 32;
  __shared__ unsigned short As[2][64 * BK];
  __shared__ unsigned short Bs[2][64 * BK];
  const int tid = threadIdx.x;
  const int wid = tid >> 6;
  const int lane = tid & 63;
  const int l15 = lane & 15;
  const int l4 = lane >> 4;
  const int bm = blockIdx.y * 64;
  const int bn = blockIdx.x * 64;
  const int wr = (wid >> 1) * 32;
  const int wc = (wid & 1) * 32;

  f32x4 acc[2][2];
#pragma unroll
  for (int i = 0; i < 2; ++i)
#pragma unroll
    for (int j = 0; j < 2; ++j) acc[i][j] = (f32x4){0.f, 0.f, 0.f, 0.f};

  const int nk = K / BK;
  auto stage = [&](int buf, int kt) {
    int c = tid;  // 256 chunks of 16B per 4KB tile
    int row = c >> 2, ch = c & 3;
    int sch = ch ^ ((row >> 1) & 3);
    GLOAD_LDS16(A + (size_t)(bm + row) * K + kt * BK + sch * 8, &As[buf][c * 8]);
    GLOAD_LDS16(W + (size_t)(bn + row) * K + kt * BK + sch * 8, &Bs[buf][c * 8]);
  };

  stage(0, 0);
  __syncthreads();

  for (int kt = 0; kt < nk; ++kt) {
    const int cur = kt & 1;
    if (kt + 1 < nk) stage(cur ^ 1, kt + 1);
    bf16x8 a[2], b[2];
#pragma unroll
    for (int mi = 0; mi < 2; ++mi) {
      int rl = wr + mi * 16 + l15;
      int ph = (rl * 64 + l4 * 16) ^ ((((unsigned)rl >> 1) & 3) << 4);
      a[mi] = *(const bf16x8*)((const char*)&As[cur][0] + ph);
    }
#pragma unroll
    for (int ni = 0; ni < 2; ++ni) {
      int rl = wc + ni * 16 + l15;
      int ph = (rl * 64 + l4 * 16) ^ ((((unsigned)rl >> 1) & 3) << 4);
      b[ni] = *(const bf16x8*)((const char*)&Bs[cur][0] + ph);
    }
#pragma unroll
    for (int mi = 0; mi < 2; ++mi)
#pragma unroll
      for (int ni = 0; ni < 2; ++ni)
        acc[mi][ni] = __builtin_amdgcn_mfma_f32_16x16x32_bf16(a[mi], b[ni], acc[mi][ni], 0, 0, 0);
    __syncthreads();
  }

#pragma unroll
  for (int mi = 0; mi < 2; ++mi) {
#pragma unroll
    for (int ni = 0; ni < 2; ++ni) {
      int gm = bm + wr + mi * 16 + l4 * 4;
      int gn = bn + wc + ni * 16 + l15;
      float bval = bias[gn];
#pragma unroll
      for (int q = 0; q < 4; ++q)
        Cf[(size_t)(gm + q) * N + gn] = (acc[mi][ni][q] + bval) * scale;
    }
  }
}

// ---------------- GEMM2: 256x512 tile, BK=32, 3-buf (144KB), wave 128x128, fused agg ------
// A: value bf16 (2048 x 1024), W: Wv bf16 (32768 x 1024)
// X[b,h,s,d] = scale * sum_r attn[m,h,r] * (A[m,:]@W[h*2048+d*32+r,:] + bias)
// Wave tile 128x128 improves MFMA:LDS-read ratio (64 MFMA : 16 b128 vs 32 : 12).
// 16x16 fragment map kept (conflict-free with XOR swizzle; 32x32 map = 4-way, round 10).
// vmcnt ledger: 6 gload_lds per slab-stage (A 2 + B 4). BODY(T) issues stage(T+2):
// queue = stage(T+1)[6] + stage(T+2)[6] -> vmcnt(6) waits exactly slab T+1. Body 30: 0.
// 3-buf rotation: stage target (T+2)%3 holds slab T-1, whose LDS reads drained at
// BODY(T-2)'s lgkmcnt(0), separated from this stage by bar(T-1). Collective ordering:
// per-wave vmcnt(6) -> barrier -> reads, as in round 8.
__global__ __launch_bounds__(512) void gemm2_k(const unsigned short* __restrict__ A,
                                               const unsigned short* __restrict__ W,
                                               const float* __restrict__ bias, float scale,
                                               const float* __restrict__ attn,
                                               unsigned short* __restrict__ X) {
  constexpr int K = 1024, BK = 32;
  extern __shared__ unsigned short lds[];  // A: 3 x 8192, B: 3 x 16384 ushorts = 144 KB
  unsigned short* Asl = lds;
  unsigned short* Bsl = lds + 3 * 8192;
  const int tid = threadIdx.x;
  const int wid = tid >> 6, lane = tid & 63;
  const int l15 = lane & 15, l4 = lane >> 4;
  const int wm = wid >> 2, wn = wid & 3;  // wave tile 128x128: rows wm*128, cols wn*128

  // XCD-aware bijective swizzle (512 blocks = 8 row x 64 col tiles): all 8 row-blocks of
  // a column tile land on one XCD -> B-panel L2 reuse.
  int orig = blockIdx.x;
  int swz = (orig & 7) * 64 + (orig >> 3);
  const int bm = (swz & 7) * 256, bn = (swz >> 3) * 512;

  auto stageA = [&](int buf, int kt) {
#pragma unroll
    for (int i = 0; i < 2; ++i) {
      int c = i * 512 + tid;  // 1024 chunks of 16B; slab = 256 rows x 4 chunks
      int row = c >> 2, ch = c & 3;
      int sch = ch ^ ((row >> 1) & 3);  // inverse swizzle on SOURCE (rule #21)
      GLOAD_LDS16(A + (size_t)(bm + row) * K + kt * BK + sch * 8, Asl + buf * 8192 + c * 8);
    }
  };
  auto stageB = [&](int buf, int kt) {
#pragma unroll
    for (int i = 0; i < 4; ++i) {
      int c = i * 512 + tid;  // 2048 chunks; slab = 512 rows x 4 chunks
      int row = c >> 2, ch = c & 3;
      int sch = ch ^ ((row >> 1) & 3);
      GLOAD_LDS16(W + (size_t)(bn + row) * K + kt * BK + sch * 8, Bsl + buf * 16384 + c * 8);
    }
  };

  f32x4 acc[8][8];
#pragma unroll
  for (int i = 0; i < 8; ++i)
#pragma unroll
    for (int j = 0; j < 8; ++j) acc[i][j] = (f32x4){0.f, 0.f, 0.f, 0.f};

  bf16x8 a[8], b[8];

#define FRAG_PH(rl) (((rl) * 64 + l4 * 16) ^ ((((unsigned)(rl) >> 1) & 3) << 4))

  // BODY: compute slab Tt from (a,b); stage Tt+2 into SB; reload a,b with slab Tt+1 (from
  // NB), each reload issued right after the frag's last MFMA use (WAR-pinned, round-6).
#define BODY(NB, SB, Tt, DO_STAGE, WN)                                                    \
  do {                                                                                    \
    if (DO_STAGE) { stageA(SB, (Tt) + 2); stageB(SB, (Tt) + 2); }                         \
    asm volatile("s_waitcnt vmcnt(" #WN ")" ::: "memory");                                \
    __builtin_amdgcn_s_barrier();                                                         \
    {                                                                                     \
      const char* _ab = (const char*)(Asl + (NB) * 8192);                                 \
      const char* _bb = (const char*)(Bsl + (NB) * 16384);                                \
      __builtin_amdgcn_s_setprio(1);                                                      \
      _Pragma("unroll") for (int mf = 0; mf < 8; ++mf) {                                  \
        _Pragma("unroll") for (int nf = 0; nf < 8; ++nf) {                                \
          acc[mf][nf] =                                                                   \
              __builtin_amdgcn_mfma_f32_16x16x32_bf16(a[mf], b[nf], acc[mf][nf], 0, 0, 0);\
          if (mf == 7)                                                                    \
            b[nf] = *(const bf16x8*)(_bb + FRAG_PH(wn * 128 + nf * 16 + l15));            \
        }                                                                                 \
        a[mf] = *(const bf16x8*)(_ab + FRAG_PH(wm * 128 + mf * 16 + l15));                \
      }                                                                                   \
      __builtin_amdgcn_s_setprio(0);                                                      \
    }                                                                                     \
    asm volatile("s_waitcnt lgkmcnt(0)" ::: "memory");                                    \
    __builtin_amdgcn_sched_barrier(0);                                                    \
  } while (0)

  // prologue: stage slabs 0,1 (12 loads); vmcnt(6) -> slab 0 landed; load slab-0 frags
  stageA(0, 0); stageB(0, 0);
  stageA(1, 1); stageB(1, 1);
  asm volatile("s_waitcnt vmcnt(6)" ::: "memory");
  __builtin_amdgcn_s_barrier();
#pragma unroll
  for (int nf = 0; nf < 8; ++nf)
    b[nf] = *(const bf16x8*)((const char*)Bsl + FRAG_PH(wn * 128 + nf * 16 + l15));
#pragma unroll
  for (int mf = 0; mf < 8; ++mf)
    a[mf] = *(const bf16x8*)((const char*)Asl + FRAG_PH(wm * 128 + mf * 16 + l15));
  asm volatile("s_waitcnt lgkmcnt(0)" ::: "memory");
  __builtin_amdgcn_sched_barrier(0);

  // bodies 0..29 (period-3 buffer pattern; body 29 stages slab 31)
  for (int T = 0; T < 30; T += 3) {
    BODY(1, 2, T, 1, 6);
    BODY(2, 0, (T + 1), 1, 6);
    BODY(0, 1, (T + 2), 1, 6);
  }
  // body 30 (slab 30 in buf 0): no stage; drain slab 31; reload slab-31 frags (buf 1)
  BODY(1, 2, 30, 0, 0);
  // tail: slab 31, registers only
  __builtin_amdgcn_s_setprio(1);
#pragma unroll
  for (int mf = 0; mf < 8; ++mf)
#pragma unroll
    for (int nf = 0; nf < 8; ++nf)
      acc[mf][nf] = __builtin_amdgcn_mfma_f32_16x16x32_bf16(a[mf], b[nf], acc[mf][nf], 0, 0, 0);
  __builtin_amdgcn_s_setprio(0);
#undef BODY
#undef FRAG_PH

  // ---- fused rule-aggregation epilogue (per-mf; wave covers 4 d-outputs) ----
  const int h = bn >> 11;                           // 2048 cols per head
  const int dbase = ((bn & 2047) + wn * 128) >> 5;  // 4 d's per wave
#pragma unroll
  for (int mf = 0; mf < 8; ++mf) {
    int gm0 = bm + wm * 128 + mf * 16 + l4 * 4;
    float red[4][4];
#pragma unroll
    for (int q = 0; q < 4; ++q)
#pragma unroll
      for (int g = 0; g < 4; ++g) red[q][g] = 0.f;
#pragma unroll
    for (int nf = 0; nf < 8; ++nf) {
      int col = bn + wn * 128 + nf * 16 + l15;
      float bval = bias[col];
      int r = (nf & 1) * 16 + l15;
      int g = nf >> 1;
#pragma unroll
      for (int q = 0; q < 4; ++q) {
        float w = attn[(size_t)(gm0 + q) * 512 + h * 32 + r];
        red[q][g] += (acc[mf][nf][q] + bval) * w;
      }
    }
#pragma unroll
    for (int q = 0; q < 4; ++q)
#pragma unroll
      for (int g = 0; g < 4; ++g) {
        float vv = red[q][g];
        for (int mask = 1; mask < 16; mask <<= 1) vv += __shfl_xor(vv, mask);
        red[q][g] = vv * scale;
      }
    if (l15 == 0) {
#pragma unroll
      for (int q = 0; q < 4; ++q) {
        int m = gm0 + q;
        int bb = m >> 10, s = m & 1023;
        size_t base = (((size_t)(bb * 16 + h)) * 1024 + s) * 64;
        unsigned w0 = (unsigned)f32_to_bf16_rne(red[q][0]) |
                      ((unsigned)f32_to_bf16_rne(red[q][1]) << 16);
        unsigned w1 = (unsigned)f32_to_bf16_rne(red[q][2]) |
                      ((unsigned)f32_to_bf16_rne(red[q][3]) << 16);
        unsigned* xp = (unsigned*)X + ((base + dbase) >> 1);
        xp[0] = w0;
        xp[1] = w1;
      }
    }
  }
}

extern "C" void kernel_launch(void* const* d_in, const int* in_sizes, int n_in, void* d_out,
                              int out_size, void* d_ws, size_t ws_size, hipStream_t stream) {
  const float* query = (const float*)d_in[0];
  const float* value = (const float*)d_in[2];
  const float* rk = (const float*)d_in[3];
  const float* rw = (const float*)d_in[4];
  const float* Wq = (const float*)d_in[5];
  const float* bq = (const float*)d_in[6];
  const float* Wv = (const float*)d_in[7];
  const float* bv = (const float*)d_in[8];
  const float* Wo = (const float*)d_in[9];
  const float* bo = (const float*)d_in[10];
  float* out = (float*)d_out;

  const float scale = 0.125f;

  char* p = (char*)d_ws;
  unsigned short* Wv_b = (unsigned short*)p; p += (size_t)33554432 * 2;
  unsigned short* Aq_b = (unsigned short*)p; p += (size_t)2097152 * 2;
  unsigned short* Av_b = (unsigned short*)p; p += (size_t)2097152 * 2;
  unsigned short* Wq_b = (unsigned short*)p; p += (size_t)1048576 * 2;
  unsigned short* Wo_b = (unsigned short*)p; p += (size_t)1048576 * 2;
  float* qf = (float*)p;   p += (size_t)2097152 * 4;
  float* attn = (float*)p; p += (size_t)1048576 * 4;
  unsigned short* X = (unsigned short*)p;

  cvt_all<<<19456, 256, 0, stream>>>(Wv, query, value, Wq, Wo, Wv_b, Aq_b, Av_b, Wq_b, Wo_b);

  // GEMM1: qf = (query @ Wq^T + bq) * scale   (2048 x 1024), 512 blocks
  gemm_bt64<<<dim3(16, 32), 256, 0, stream>>>(Aq_b, Wq_b, bq, scale, 2048, 1024, 1024, qf);
  // fuzzy membership + softmax
  fuzzy2_k<<<dim3(16, 16), 256, 0, stream>>>(qf, rk, rw, attn);
  // GEMM2 fused (256x512, 3-buf, 144KB dynamic LDS, wave 128x128)
  hipFuncSetAttribute((const void*)gemm2_k, hipFuncAttributeMaxDynamicSharedMemorySize, 147456);
  gemm2_k<<<512, 512, 147456, stream>>>(Av_b, Wv_b, bv, scale, attn, X);
  // GEMM3: out = X @ Wo^T + bo
  gemm_bt64<<<dim3(16, 32), 256, 0, stream>>>(X, Wo_b, bo, 1.0f, 2048, 1024, 1024, out);
}

// Round 12
// 256.638 us; speedup vs baseline: 5.6468x; 5.6468x over previous
//
#include <hip/hip_runtime.h>
#include <hip/hip_bf16.h>
#include <cstdint>

typedef float f32x4 __attribute__((ext_vector_type(4)));
typedef short bf16x8 __attribute__((ext_vector_type(8)));

__device__ __forceinline__ unsigned short f32_to_bf16_rne(float f) {
  unsigned int u = __float_as_uint(f);
  return (unsigned short)((u + 0x7FFFu + ((u >> 16) & 1u)) >> 16);
}

#define GLOAD_LDS16(gptr, lptr)                                                             \
  __builtin_amdgcn_global_load_lds((const __attribute__((address_space(1))) unsigned int*)(gptr), \
                                   (__attribute__((address_space(3))) unsigned int*)(lptr), 16, 0, 0)

// ---------------- fused f32 -> bf16 for q, v, Wq, Wo (8 elems / thread) -------------------
// (Wv is no longer pre-converted: gemm2 stages it from f32 directly.)
__global__ __launch_bounds__(256) void cvt_all(const float* __restrict__ q,
                                               const float* __restrict__ v,
                                               const float* __restrict__ wq,
                                               const float* __restrict__ wo,
                                               unsigned short* __restrict__ qb,
                                               unsigned short* __restrict__ vb,
                                               unsigned short* __restrict__ wqb,
                                               unsigned short* __restrict__ wob) {
  int i = blockIdx.x * 256 + threadIdx.x;  // chunk of 8 floats
  const float* src;
  unsigned short* dst;
  int off;
  if (i < 262144)      { src = q;  dst = qb;  off = i; }
  else if (i < 524288) { src = v;  dst = vb;  off = i - 262144; }
  else if (i < 655360) { src = wq; dst = wqb; off = i - 524288; }
  else                 { src = wo; dst = wob; off = i - 655360; }
  const float4* s = (const float4*)src;
  float4 a = s[2 * off], b = s[2 * off + 1];
  uint4 o;
  o.x = (unsigned)f32_to_bf16_rne(a.x) | ((unsigned)f32_to_bf16_rne(a.y) << 16);
  o.y = (unsigned)f32_to_bf16_rne(a.z) | ((unsigned)f32_to_bf16_rne(a.w) << 16);
  o.z = (unsigned)f32_to_bf16_rne(b.x) | ((unsigned)f32_to_bf16_rne(b.y) << 16);
  o.w = (unsigned)f32_to_bf16_rne(b.z) | ((unsigned)f32_to_bf16_rne(b.w) << 16);
  ((uint4*)dst)[off] = o;
}

// ---------------- fuzzy membership + softmax: LDS-staged rules, one head per block --------
__global__ __launch_bounds__(256) void fuzzy2_k(const float* __restrict__ qf,
                                                const float* __restrict__ rk,
                                                const float* __restrict__ rw,
                                                float* __restrict__ attn) {
  __shared__ float lk[32][65];
  __shared__ float lc[32][65];
  const int tid = threadIdx.x;
  const int h = blockIdx.y;
  const int mbase = blockIdx.x * 128;

  for (int idx = tid; idx < 2048; idx += 256) {
    int r = idx >> 6, d = idx & 63;
    lk[r][d] = rk[(size_t)(h * 32 + r) * 64 + d];
    float w = rw[(size_t)(h * 32 + r) * 64 + d];
    lc[r][d] = 0.0078125f / (w * w);
  }
  __syncthreads();

  const int g = tid >> 5;
  const int r = tid & 31;
#pragma unroll 1
  for (int it = 0; it < 16; ++it) {
    int m = mbase + it * 8 + g;
    const float* qrow = qf + (size_t)m * 1024 + h * 64;
    float acc = 0.f;
#pragma unroll
    for (int d0 = 0; d0 < 64; d0 += 4) {
      float4 q4 = *(const float4*)(qrow + d0);
      const float* qp = (const float*)&q4;
#pragma unroll
      for (int j = 0; j < 4; ++j) {
        float diff = qp[j] - lk[r][d0 + j];
        acc += lc[r][d0 + j] * diff * diff;
      }
    }
    float z = -acc;
    float mx = z;
#pragma unroll
    for (int mask = 16; mask >= 1; mask >>= 1) mx = fmaxf(mx, __shfl_xor(mx, mask));
    float e = __expf(z - mx);
    float s = e;
#pragma unroll
    for (int mask = 16; mask >= 1; mask >>= 1) s += __shfl_xor(s, mask);
    attn[(size_t)m * 512 + h * 32 + r] = e / s;
  }
}

// ---------------- small bf16 GEMM (64x64 tile, 512 blocks, ~8/CU): C = (A@W^T+b)*scale ----
__global__ __launch_bounds__(256) void gemm_bt64(const unsigned short* __restrict__ A,
                                                 const unsigned short* __restrict__ W,
                                                 const float* __restrict__ bias, float scale,
                                                 int M, int N, int K, float* __restrict__ Cf) {
  constexpr int BK = 32;
  __shared__ unsigned short As[2][64 * BK];
  __shared__ unsigned short Bs[2][64 * BK];
  const int tid = threadIdx.x;
  const int wid = tid >> 6;
  const int lane = tid & 63;
  const int l15 = lane & 15;
  const int l4 = lane >> 4;
  const int bm = blockIdx.y * 64;
  const int bn = blockIdx.x * 64;
  const int wr = (wid >> 1) * 32;
  const int wc = (wid & 1) * 32;

  f32x4 acc[2][2];
#pragma unroll
  for (int i = 0; i < 2; ++i)
#pragma unroll
    for (int j = 0; j < 2; ++j) acc[i][j] = (f32x4){0.f, 0.f, 0.f, 0.f};

  const int nk = K / BK;
  auto stage = [&](int buf, int kt) {
    int c = tid;  // 256 chunks of 16B per 4KB tile
    int row = c >> 2, ch = c & 3;
    int sch = ch ^ ((row >> 1) & 3);
    GLOAD_LDS16(A + (size_t)(bm + row) * K + kt * BK + sch * 8, &As[buf][c * 8]);
    GLOAD_LDS16(W + (size_t)(bn + row) * K + kt * BK + sch * 8, &Bs[buf][c * 8]);
  };

  stage(0, 0);
  __syncthreads();

  for (int kt = 0; kt < nk; ++kt) {
    const int cur = kt & 1;
    if (kt + 1 < nk) stage(cur ^ 1, kt + 1);
    bf16x8 a[2], b[2];
#pragma unroll
    for (int mi = 0; mi < 2; ++mi) {
      int rl = wr + mi * 16 + l15;
      int ph = (rl * 64 + l4 * 16) ^ ((((unsigned)rl >> 1) & 3) << 4);
      a[mi] = *(const bf16x8*)((const char*)&As[cur][0] + ph);
    }
#pragma unroll
    for (int ni = 0; ni < 2; ++ni) {
      int rl = wc + ni * 16 + l15;
      int ph = (rl * 64 + l4 * 16) ^ ((((unsigned)rl >> 1) & 3) << 4);
      b[ni] = *(const bf16x8*)((const char*)&Bs[cur][0] + ph);
    }
#pragma unroll
    for (int mi = 0; mi < 2; ++mi)
#pragma unroll
      for (int ni = 0; ni < 2; ++ni)
        acc[mi][ni] = __builtin_amdgcn_mfma_f32_16x16x32_bf16(a[mi], b[ni], acc[mi][ni], 0, 0, 0);
    __syncthreads();
  }

#pragma unroll
  for (int mi = 0; mi < 2; ++mi) {
#pragma unroll
    for (int ni = 0; ni < 2; ++ni) {
      int gm = bm + wr + mi * 16 + l4 * 4;
      int gn = bn + wc + ni * 16 + l15;
      float bval = bias[gn];
#pragma unroll
      for (int q = 0; q < 4; ++q)
        Cf[(size_t)(gm + q) * N + gn] = (acc[mi][ni][q] + bval) * scale;
    }
  }
}

// ---------------- GEMM2: 256x256, BK=32, 4-buf (round-8 schedule), B staged from f32 ------
// A: value bf16 (2048 x 1024), W32: Wv f32 (32768 x 1024)
// X[b,h,s,d] = scale * sum_r attn[m,h,r] * (A[m,:]@W[h*2048+d*32+r,:] + bias)
// B-staging is reg-staged from f32 with in-kernel bf16 conversion (bitwise-identical
// rounding to the old cvt pass). Ledger per BODY(T):
//   entry queue: [loadB(T+1) x4, gloadA(T+1) x2]
//   CVT: vmcnt(2) drains loadB(T+1) -> cvt -> 2x ds_write_b128 into buf (T+1)&3
//        (old content = slab T-3, reads drained 3 barriers earlier)
//   issue loadB(T+2) x4 + gloadA(T+2) x2
//   vmcnt(6) drains gloadA(T+1); lgkmcnt(0) makes writes visible; barrier
//   cluster: 32 MFMA on slab T + interleaved prefetch reads of slab T+1 frags (round-8)
__global__ __launch_bounds__(512) void gemm2_k(const unsigned short* __restrict__ A,
                                               const float* __restrict__ W32,
                                               const float* __restrict__ bias, float scale,
                                               const float* __restrict__ attn,
                                               unsigned short* __restrict__ X) {
  constexpr int K = 1024, BK = 32;
  extern __shared__ unsigned short lds[];  // A: 4 x 8192, B: 4 x 8192 ushorts = 128 KB
  unsigned short* Asl = lds;
  unsigned short* Bsl = lds + 4 * 8192;
  const int tid = threadIdx.x;
  const int wid = tid >> 6, lane = tid & 63;
  const int l15 = lane & 15, l4 = lane >> 4;
  const int wm = wid >> 2, wn = wid & 3;  // wave tile 128x64

  // XCD-aware bijective swizzle: contiguous col-tile strip per XCD (B-panel L2 reuse)
  int orig = blockIdx.x;
  int swz = (orig & 7) * 128 + (orig >> 3);
  const int bm = (swz & 7) * 256, bn = (swz >> 3) * 256;

  auto stageA = [&](int buf, int kt) {
#pragma unroll
    for (int i = 0; i < 2; ++i) {
      int c = i * 512 + tid;  // 1024 chunks of 16B; slab = 256 rows x 4 chunks
      int row = c >> 2, ch = c & 3;
      int sch = ch ^ ((row >> 1) & 3);  // inverse swizzle on SOURCE (rule #21)
      GLOAD_LDS16(A + (size_t)(bm + row) * K + kt * BK + sch * 8, Asl + buf * 8192 + c * 8);
    }
  };

  f32x4 acc[8][4];
#pragma unroll
  for (int i = 0; i < 8; ++i)
#pragma unroll
    for (int j = 0; j < 4; ++j) acc[i][j] = (f32x4){0.f, 0.f, 0.f, 0.f};

  bf16x8 a0[8], a1[8], b0[4], b1[4];
  float4 g00, g01, g10, g11;  // staged f32 B chunks (live one body)

#define FRAG_PH(rl) (((rl) * 64 + l4 * 16) ^ ((((unsigned)rl >> 1) & 3) << 4))
#define PKR(lo, hi) ((unsigned)f32_to_bf16_rne(lo) | ((unsigned)f32_to_bf16_rne(hi) << 16))

  // issue the 4 f32 loads for B slab KT (queue position = old stageB)
#define LOAD_B32(KT)                                                                      \
  do {                                                                                    \
    int _c = tid, _row = _c >> 2, _sch = (_c & 3) ^ ((_row >> 1) & 3);                    \
    const float* _s0 = W32 + (size_t)(bn + _row) * 1024 + (KT) * 32 + _sch * 8;           \
    g00 = *(const float4*)_s0;                                                            \
    g01 = *(const float4*)(_s0 + 4);                                                      \
    _c = tid + 512; _row = _c >> 2; _sch = (_c & 3) ^ ((_row >> 1) & 3);                  \
    const float* _s1 = W32 + (size_t)(bn + _row) * 1024 + (KT) * 32 + _sch * 8;           \
    g10 = *(const float4*)_s1;                                                            \
    g11 = *(const float4*)(_s1 + 4);                                                      \
  } while (0)

  // finish B slab Tt+1: wait its loads (oldest 4 of 6 outstanding), cvt, write to LDS
#define CVT_B(Tt)                                                                         \
  do {                                                                                    \
    asm volatile("s_waitcnt vmcnt(2)" ::: "memory");                                      \
    unsigned short* _dst = Bsl + (((Tt) + 1) & 3) * 8192;                                 \
    uint4 _p0, _p1;                                                                       \
    _p0.x = PKR(g00.x, g00.y); _p0.y = PKR(g00.z, g00.w);                                 \
    _p0.z = PKR(g01.x, g01.y); _p0.w = PKR(g01.z, g01.w);                                 \
    _p1.x = PKR(g10.x, g10.y); _p1.y = PKR(g10.z, g10.w);                                 \
    _p1.z = PKR(g11.x, g11.y); _p1.w = PKR(g11.z, g11.w);                                 \
    *reinterpret_cast<uint4*>(_dst + tid * 8) = _p0;                                      \
    *reinterpret_cast<uint4*>(_dst + (tid + 512) * 8) = _p1;                              \
  } while (0)

#define BODY(aC, aN, bC, bN, Tt, HAS_CVT, DO_STAGE, WN)                                   \
  do {                                                                                    \
    if (HAS_CVT) CVT_B(Tt);                                                               \
    if (DO_STAGE) { LOAD_B32((Tt) + 2); stageA(((Tt) + 2) & 3, (Tt) + 2); }               \
    asm volatile("s_waitcnt vmcnt(" #WN ")" ::: "memory");                                \
    asm volatile("s_waitcnt lgkmcnt(0)" ::: "memory");                                    \
    __builtin_amdgcn_s_barrier();                                                         \
    {                                                                                     \
      const char* _ab = (const char*)(Asl + (((Tt) + 1) & 3) * 8192);                     \
      const char* _bb = (const char*)(Bsl + (((Tt) + 1) & 3) * 8192);                     \
      __builtin_amdgcn_s_setprio(1);                                                      \
      _Pragma("unroll") for (int mf = 0; mf < 8; ++mf) {                                  \
        _Pragma("unroll") for (int nf = 0; nf < 4; ++nf)                                  \
          acc[mf][nf] =                                                                   \
              __builtin_amdgcn_mfma_f32_16x16x32_bf16(aC[mf], bC[nf], acc[mf][nf], 0, 0, 0); \
        if (mf < 4) {                                                                     \
          aN[mf] = *(const bf16x8*)(_ab + FRAG_PH(wm * 128 + mf * 16 + l15));             \
          bN[mf] = *(const bf16x8*)(_bb + FRAG_PH(wn * 64 + mf * 16 + l15));              \
        } else if (mf < 6) {                                                              \
          int i0 = 2 * mf - 4, i1 = 2 * mf - 3;                                           \
          aN[i0] = *(const bf16x8*)(_ab + FRAG_PH(wm * 128 + i0 * 16 + l15));             \
          aN[i1] = *(const bf16x8*)(_ab + FRAG_PH(wm * 128 + i1 * 16 + l15));             \
        }                                                                                 \
      }                                                                                   \
      __builtin_amdgcn_s_setprio(0);                                                      \
    }                                                                                     \
    asm volatile("s_waitcnt lgkmcnt(0)" ::: "memory");                                    \
    __builtin_amdgcn_sched_barrier(0);                                                    \
  } while (0)

  // prologue: slabs 0,1. B via f32-reg-cvt; A via gload_lds.
  LOAD_B32(0);
  stageA(0, 0);
  CVT_B(-1);  // vmcnt(2): drains loadB(0); writes buf 0
  LOAD_B32(1);
  stageA(1, 1);
  CVT_B(0);   // vmcnt(2): drains gloadA(0)+loadB(1), leaves gloadA(1); writes buf 1
  asm volatile("s_waitcnt lgkmcnt(0)" ::: "memory");
  __builtin_amdgcn_s_barrier();
#pragma unroll
  for (int nf = 0; nf < 4; ++nf)
    b0[nf] = *(const bf16x8*)((const char*)Bsl + FRAG_PH(wn * 64 + nf * 16 + l15));
#pragma unroll
  for (int mf = 0; mf < 8; ++mf)
    a0[mf] = *(const bf16x8*)((const char*)Asl + FRAG_PH(wm * 128 + mf * 16 + l15));
  asm volatile("s_waitcnt lgkmcnt(0)" ::: "memory");
  __builtin_amdgcn_sched_barrier(0);

  // bodies: 0 (no cvt needed), 1..29 uniform, 30 (drain), tail 31
  BODY(a0, a1, b0, b1, 0, 0, 1, 6);
  for (int T = 1; T < 29; T += 2) {
    BODY(a1, a0, b1, b0, T, 1, 1, 6);
    BODY(a0, a1, b0, b1, T + 1, 1, 1, 6);
  }
  BODY(a1, a0, b1, b0, 29, 1, 1, 6);  // computes 29, stages slab 31
  BODY(a0, a1, b0, b1, 30, 1, 0, 0);  // computes 30, cvt+write B31, drain A31
  // tail: slab 31, registers only
  __builtin_amdgcn_s_setprio(1);
#pragma unroll
  for (int mf = 0; mf < 8; ++mf)
#pragma unroll
    for (int nf = 0; nf < 4; ++nf)
      acc[mf][nf] = __builtin_amdgcn_mfma_f32_16x16x32_bf16(a1[mf], b1[nf], acc[mf][nf], 0, 0, 0);
  __builtin_amdgcn_s_setprio(0);
#undef BODY
#undef CVT_B
#undef LOAD_B32
#undef FRAG_PH

  // ---- fused rule-aggregation epilogue (per-mf to bound register pressure) ----
  const int h = bn >> 11;                          // 2048 cols per head
  const int dbase = ((bn & 2047) + wn * 64) >> 5;  // even
#pragma unroll
  for (int mf = 0; mf < 8; ++mf) {
    int gm0 = bm + wm * 128 + mf * 16 + l4 * 4;
    float red[4][2];
#pragma unroll
    for (int q = 0; q < 4; ++q) { red[q][0] = 0.f; red[q][1] = 0.f; }
#pragma unroll
    for (int nf = 0; nf < 4; ++nf) {
      int col = bn + wn * 64 + nf * 16 + l15;
      float bval = bias[col];
      int r = (nf & 1) * 16 + l15;
      int g = nf >> 1;
#pragma unroll
      for (int q = 0; q < 4; ++q) {
        float w = attn[(size_t)(gm0 + q) * 512 + h * 32 + r];
        red[q][g] += (acc[mf][nf][q] + bval) * w;
      }
    }
#pragma unroll
    for (int q = 0; q < 4; ++q)
#pragma unroll
      for (int g = 0; g < 2; ++g) {
        float vv = red[q][g];
        for (int mask = 1; mask < 16; mask <<= 1) vv += __shfl_xor(vv, mask);
        red[q][g] = vv * scale;
      }
    if (l15 == 0) {
#pragma unroll
      for (int q = 0; q < 4; ++q) {
        int m = gm0 + q;
        int bb = m >> 10, s = m & 1023;
        size_t base = (((size_t)(bb * 16 + h)) * 1024 + s) * 64;
        unsigned lo = f32_to_bf16_rne(red[q][0]);
        unsigned hi = f32_to_bf16_rne(red[q][1]);
        ((unsigned*)X)[(base + dbase) >> 1] = lo | (hi << 16);
      }
    }
  }
}

extern "C" void kernel_launch(void* const* d_in, const int* in_sizes, int n_in, void* d_out,
                              int out_size, void* d_ws, size_t ws_size, hipStream_t stream) {
  const float* query = (const float*)d_in[0];
  const float* value = (const float*)d_in[2];
  const float* rk = (const float*)d_in[3];
  const float* rw = (const float*)d_in[4];
  const float* Wq = (const float*)d_in[5];
  const float* bq = (const float*)d_in[6];
  const float* Wv = (const float*)d_in[7];
  const float* bv = (const float*)d_in[8];
  const float* Wo = (const float*)d_in[9];
  const float* bo = (const float*)d_in[10];
  float* out = (float*)d_out;

  const float scale = 0.125f;

  char* p = (char*)d_ws;
  unsigned short* Aq_b = (unsigned short*)p; p += (size_t)2097152 * 2;
  unsigned short* Av_b = (unsigned short*)p; p += (size_t)2097152 * 2;
  unsigned short* Wq_b = (unsigned short*)p; p += (size_t)1048576 * 2;
  unsigned short* Wo_b = (unsigned short*)p; p += (size_t)1048576 * 2;
  float* qf = (float*)p;   p += (size_t)2097152 * 4;
  float* attn = (float*)p; p += (size_t)1048576 * 4;
  unsigned short* X = (unsigned short*)p;

  // convert q, v, Wq, Wo only (786432 chunks of 8 floats)
  cvt_all<<<3072, 256, 0, stream>>>(query, value, Wq, Wo, Aq_b, Av_b, Wq_b, Wo_b);

  // GEMM1: qf = (query @ Wq^T + bq) * scale   (2048 x 1024), 512 blocks
  gemm_bt64<<<dim3(16, 32), 256, 0, stream>>>(Aq_b, Wq_b, bq, scale, 2048, 1024, 1024, qf);
  // fuzzy membership + softmax
  fuzzy2_k<<<dim3(16, 16), 256, 0, stream>>>(qf, rk, rw, attn);
  // GEMM2 fused (round-8 schedule; B staged from f32 Wv in-kernel)
  hipFuncSetAttribute((const void*)gemm2_k, hipFuncAttributeMaxDynamicSharedMemorySize, 131072);
  gemm2_k<<<1024, 512, 131072, stream>>>(Av_b, Wv, bv, scale, attn, X);
  // GEMM3: out = X @ Wo^T + bo
  gemm_bt64<<<dim3(16, 32), 256, 0, stream>>>(X, Wo_b, bo, 1.0f, 2048, 1024, 1024, out);
}

// Round 13
// 256.492 us; speedup vs baseline: 5.6500x; 1.0006x over previous
//
#include <hip/hip_runtime.h>
#include <hip/hip_bf16.h>
#include <cstdint>

typedef float f32x4 __attribute__((ext_vector_type(4)));
typedef short bf16x8 __attribute__((ext_vector_type(8)));

__device__ __forceinline__ unsigned short f32_to_bf16_rne(float f) {
  unsigned int u = __float_as_uint(f);
  return (unsigned short)((u + 0x7FFFu + ((u >> 16) & 1u)) >> 16);
}

#define GLOAD_LDS16(gptr, lptr)                                                             \
  __builtin_amdgcn_global_load_lds((const __attribute__((address_space(1))) unsigned int*)(gptr), \
                                   (__attribute__((address_space(3))) unsigned int*)(lptr), 16, 0, 0)

// ---------------- fused f32 -> bf16 for q, v, Wq, Wo (8 elems / thread) -------------------
// (Wv is not pre-converted: gemm2 stages it from f32 directly.)
__global__ __launch_bounds__(256) void cvt_all(const float* __restrict__ q,
                                               const float* __restrict__ v,
                                               const float* __restrict__ wq,
                                               const float* __restrict__ wo,
                                               unsigned short* __restrict__ qb,
                                               unsigned short* __restrict__ vb,
                                               unsigned short* __restrict__ wqb,
                                               unsigned short* __restrict__ wob) {
  int i = blockIdx.x * 256 + threadIdx.x;  // chunk of 8 floats
  const float* src;
  unsigned short* dst;
  int off;
  if (i < 262144)      { src = q;  dst = qb;  off = i; }
  else if (i < 524288) { src = v;  dst = vb;  off = i - 262144; }
  else if (i < 655360) { src = wq; dst = wqb; off = i - 524288; }
  else                 { src = wo; dst = wob; off = i - 655360; }
  const float4* s = (const float4*)src;
  float4 a = s[2 * off], b = s[2 * off + 1];
  uint4 o;
  o.x = (unsigned)f32_to_bf16_rne(a.x) | ((unsigned)f32_to_bf16_rne(a.y) << 16);
  o.y = (unsigned)f32_to_bf16_rne(a.z) | ((unsigned)f32_to_bf16_rne(a.w) << 16);
  o.z = (unsigned)f32_to_bf16_rne(b.x) | ((unsigned)f32_to_bf16_rne(b.y) << 16);
  o.w = (unsigned)f32_to_bf16_rne(b.z) | ((unsigned)f32_to_bf16_rne(b.w) << 16);
  ((uint4*)dst)[off] = o;
}

// ---------------- fuzzy membership + softmax: LDS-staged rules, one head per block --------
__global__ __launch_bounds__(256) void fuzzy2_k(const float* __restrict__ qf,
                                                const float* __restrict__ rk,
                                                const float* __restrict__ rw,
                                                float* __restrict__ attn) {
  __shared__ float lk[32][65];
  __shared__ float lc[32][65];
  const int tid = threadIdx.x;
  const int h = blockIdx.y;
  const int mbase = blockIdx.x * 128;

  for (int idx = tid; idx < 2048; idx += 256) {
    int r = idx >> 6, d = idx & 63;
    lk[r][d] = rk[(size_t)(h * 32 + r) * 64 + d];
    float w = rw[(size_t)(h * 32 + r) * 64 + d];
    lc[r][d] = 0.0078125f / (w * w);
  }
  __syncthreads();

  const int g = tid >> 5;
  const int r = tid & 31;
#pragma unroll 1
  for (int it = 0; it < 16; ++it) {
    int m = mbase + it * 8 + g;
    const float* qrow = qf + (size_t)m * 1024 + h * 64;
    float acc = 0.f;
#pragma unroll
    for (int d0 = 0; d0 < 64; d0 += 4) {
      float4 q4 = *(const float4*)(qrow + d0);
      const float* qp = (const float*)&q4;
#pragma unroll
      for (int j = 0; j < 4; ++j) {
        float diff = qp[j] - lk[r][d0 + j];
        acc += lc[r][d0 + j] * diff * diff;
      }
    }
    float z = -acc;
    float mx = z;
#pragma unroll
    for (int mask = 16; mask >= 1; mask >>= 1) mx = fmaxf(mx, __shfl_xor(mx, mask));
    float e = __expf(z - mx);
    float s = e;
#pragma unroll
    for (int mask = 16; mask >= 1; mask >>= 1) s += __shfl_xor(s, mask);
    attn[(size_t)m * 512 + h * 32 + r] = e / s;
  }
}

// ---------------- small bf16 GEMM (64x64 tile, 512 blocks, ~8/CU): C = (A@W^T+b)*scale ----
__global__ __launch_bounds__(256) void gemm_bt64(const unsigned short* __restrict__ A,
                                                 const unsigned short* __restrict__ W,
                                                 const float* __restrict__ bias, float scale,
                                                 int M, int N, int K, float* __restrict__ Cf) {
  constexpr int BK = 32;
  __shared__ unsigned short As[2][64 * BK];
  __shared__ unsigned short Bs[2][64 * BK];
  const int tid = threadIdx.x;
  const int wid = tid >> 6;
  const int lane = tid & 63;
  const int l15 = lane & 15;
  const int l4 = lane >> 4;
  const int bm = blockIdx.y * 64;
  const int bn = blockIdx.x * 64;
  const int wr = (wid >> 1) * 32;
  const int wc = (wid & 1) * 32;

  f32x4 acc[2][2];
#pragma unroll
  for (int i = 0; i < 2; ++i)
#pragma unroll
    for (int j = 0; j < 2; ++j) acc[i][j] = (f32x4){0.f, 0.f, 0.f, 0.f};

  const int nk = K / BK;
  auto stage = [&](int buf, int kt) {
    int c = tid;  // 256 chunks of 16B per 4KB tile
    int row = c >> 2, ch = c & 3;
    int sch = ch ^ ((row >> 1) & 3);
    GLOAD_LDS16(A + (size_t)(bm + row) * K + kt * BK + sch * 8, &As[buf][c * 8]);
    GLOAD_LDS16(W + (size_t)(bn + row) * K + kt * BK + sch * 8, &Bs[buf][c * 8]);
  };

  stage(0, 0);
  __syncthreads();

  for (int kt = 0; kt < nk; ++kt) {
    const int cur = kt & 1;
    if (kt + 1 < nk) stage(cur ^ 1, kt + 1);
    bf16x8 a[2], b[2];
#pragma unroll
    for (int mi = 0; mi < 2; ++mi) {
      int rl = wr + mi * 16 + l15;
      int ph = (rl * 64 + l4 * 16) ^ ((((unsigned)rl >> 1) & 3) << 4);
      a[mi] = *(const bf16x8*)((const char*)&As[cur][0] + ph);
    }
#pragma unroll
    for (int ni = 0; ni < 2; ++ni) {
      int rl = wc + ni * 16 + l15;
      int ph = (rl * 64 + l4 * 16) ^ ((((unsigned)rl >> 1) & 3) << 4);
      b[ni] = *(const bf16x8*)((const char*)&Bs[cur][0] + ph);
    }
#pragma unroll
    for (int mi = 0; mi < 2; ++mi)
#pragma unroll
      for (int ni = 0; ni < 2; ++ni)
        acc[mi][ni] = __builtin_amdgcn_mfma_f32_16x16x32_bf16(a[mi], b[ni], acc[mi][ni], 0, 0, 0);
    __syncthreads();
  }

#pragma unroll
  for (int mi = 0; mi < 2; ++mi) {
#pragma unroll
    for (int ni = 0; ni < 2; ++ni) {
      int gm = bm + wr + mi * 16 + l4 * 4;
      int gn = bn + wc + ni * 16 + l15;
      float bval = bias[gn];
#pragma unroll
      for (int q = 0; q < 4; ++q)
        Cf[(size_t)(gm + q) * N + gn] = (acc[mi][ni][q] + bval) * scale;
    }
  }
}

// ---------------- GEMM2: 256x256, BK=32, 4-buf (round-8 schedule), B staged from f32 ------
// A: value bf16 (2048 x 1024), W32: Wv f32 (32768 x 1024)
// X[b,h,s,d] = scale * sum_r attn[m,h,r] * (A[m,:]@W[h*2048+d*32+r,:] + bias)
// __launch_bounds__(512, 2): dynamic LDS hides occupancy from the compiler, which then
// defaults to a 128-VGPR cap for 512-thread blocks (measured r3/r11/r12: demand >128 =>
// scratch spill). 128 KB LDS => 1 block/CU => 2 waves/SIMD, so declaring 2 waves/EU is
// free and raises the cap to 256 (m69 steps).
// Ledger per BODY(T):
//   entry queue: [loadB(T+1) x4, gloadA(T+1) x2]
//   CVT: vmcnt(2) drains loadB(T+1) -> cvt -> 2x ds_write_b128 into buf (T+1)&3
//        (old content = slab T-3, reads drained 3 barriers earlier)
//   issue loadB(T+2) x4 + gloadA(T+2) x2
//   vmcnt(6) drains gloadA(T+1); lgkmcnt(0) makes writes visible; barrier
//   cluster: 32 MFMA on slab T + interleaved prefetch reads of slab T+1 frags (round-8)
__global__ __launch_bounds__(512, 2) void gemm2_k(const unsigned short* __restrict__ A,
                                                  const float* __restrict__ W32,
                                                  const float* __restrict__ bias, float scale,
                                                  const float* __restrict__ attn,
                                                  unsigned short* __restrict__ X) {
  constexpr int K = 1024, BK = 32;
  extern __shared__ unsigned short lds[];  // A: 4 x 8192, B: 4 x 8192 ushorts = 128 KB
  unsigned short* Asl = lds;
  unsigned short* Bsl = lds + 4 * 8192;
  const int tid = threadIdx.x;
  const int wid = tid >> 6, lane = tid & 63;
  const int l15 = lane & 15, l4 = lane >> 4;
  const int wm = wid >> 2, wn = wid & 3;  // wave tile 128x64

  // XCD-aware bijective swizzle: contiguous col-tile strip per XCD (B-panel L2 reuse)
  int orig = blockIdx.x;
  int swz = (orig & 7) * 128 + (orig >> 3);
  const int bm = (swz & 7) * 256, bn = (swz >> 3) * 256;

  auto stageA = [&](int buf, int kt) {
#pragma unroll
    for (int i = 0; i < 2; ++i) {
      int c = i * 512 + tid;  // 1024 chunks of 16B; slab = 256 rows x 4 chunks
      int row = c >> 2, ch = c & 3;
      int sch = ch ^ ((row >> 1) & 3);  // inverse swizzle on SOURCE (rule #21)
      GLOAD_LDS16(A + (size_t)(bm + row) * K + kt * BK + sch * 8, Asl + buf * 8192 + c * 8);
    }
  };

  f32x4 acc[8][4];
#pragma unroll
  for (int i = 0; i < 8; ++i)
#pragma unroll
    for (int j = 0; j < 4; ++j) acc[i][j] = (f32x4){0.f, 0.f, 0.f, 0.f};

  bf16x8 a0[8], a1[8], b0[4], b1[4];
  float4 g00, g01, g10, g11;  // staged f32 B chunks (live one body)

#define FRAG_PH(rl) (((rl) * 64 + l4 * 16) ^ ((((unsigned)rl >> 1) & 3) << 4))
#define PKR(lo, hi) ((unsigned)f32_to_bf16_rne(lo) | ((unsigned)f32_to_bf16_rne(hi) << 16))

  // issue the 4 f32 loads for B slab KT (queue position = old stageB)
#define LOAD_B32(KT)                                                                      \
  do {                                                                                    \
    int _c = tid, _row = _c >> 2, _sch = (_c & 3) ^ ((_row >> 1) & 3);                    \
    const float* _s0 = W32 + (size_t)(bn + _row) * 1024 + (KT) * 32 + _sch * 8;           \
    g00 = *(const float4*)_s0;                                                            \
    g01 = *(const float4*)(_s0 + 4);                                                      \
    _c = tid + 512; _row = _c >> 2; _sch = (_c & 3) ^ ((_row >> 1) & 3);                  \
    const float* _s1 = W32 + (size_t)(bn + _row) * 1024 + (KT) * 32 + _sch * 8;           \
    g10 = *(const float4*)_s1;                                                            \
    g11 = *(const float4*)(_s1 + 4);                                                      \
  } while (0)

  // finish B slab Tt+1: wait its loads (oldest 4 of 6 outstanding), cvt, write to LDS
#define CVT_B(Tt)                                                                         \
  do {                                                                                    \
    asm volatile("s_waitcnt vmcnt(2)" ::: "memory");                                      \
    unsigned short* _dst = Bsl + (((Tt) + 1) & 3) * 8192;                                 \
    uint4 _p0, _p1;                                                                       \
    _p0.x = PKR(g00.x, g00.y); _p0.y = PKR(g00.z, g00.w);                                 \
    _p0.z = PKR(g01.x, g01.y); _p0.w = PKR(g01.z, g01.w);                                 \
    _p1.x = PKR(g10.x, g10.y); _p1.y = PKR(g10.z, g10.w);                                 \
    _p1.z = PKR(g11.x, g11.y); _p1.w = PKR(g11.z, g11.w);                                 \
    *reinterpret_cast<uint4*>(_dst + tid * 8) = _p0;                                      \
    *reinterpret_cast<uint4*>(_dst + (tid + 512) * 8) = _p1;                              \
  } while (0)

#define BODY(aC, aN, bC, bN, Tt, HAS_CVT, DO_STAGE, WN)                                   \
  do {                                                                                    \
    if (HAS_CVT) CVT_B(Tt);                                                               \
    if (DO_STAGE) { LOAD_B32((Tt) + 2); stageA(((Tt) + 2) & 3, (Tt) + 2); }               \
    asm volatile("s_waitcnt vmcnt(" #WN ")" ::: "memory");                                \
    asm volatile("s_waitcnt lgkmcnt(0)" ::: "memory");                                    \
    __builtin_amdgcn_s_barrier();                                                         \
    {                                                                                     \
      const char* _ab = (const char*)(Asl + (((Tt) + 1) & 3) * 8192);                     \
      const char* _bb = (const char*)(Bsl + (((Tt) + 1) & 3) * 8192);                     \
      __builtin_amdgcn_s_setprio(1);                                                      \
      _Pragma("unroll") for (int mf = 0; mf < 8; ++mf) {                                  \
        _Pragma("unroll") for (int nf = 0; nf < 4; ++nf)                                  \
          acc[mf][nf] =                                                                   \
              __builtin_amdgcn_mfma_f32_16x16x32_bf16(aC[mf], bC[nf], acc[mf][nf], 0, 0, 0); \
        if (mf < 4) {                                                                     \
          aN[mf] = *(const bf16x8*)(_ab + FRAG_PH(wm * 128 + mf * 16 + l15));             \
          bN[mf] = *(const bf16x8*)(_bb + FRAG_PH(wn * 64 + mf * 16 + l15));              \
        } else if (mf < 6) {                                                              \
          int i0 = 2 * mf - 4, i1 = 2 * mf - 3;                                           \
          aN[i0] = *(const bf16x8*)(_ab + FRAG_PH(wm * 128 + i0 * 16 + l15));             \
          aN[i1] = *(const bf16x8*)(_ab + FRAG_PH(wm * 128 + i1 * 16 + l15));             \
        }                                                                                 \
      }                                                                                   \
      __builtin_amdgcn_s_setprio(0);                                                      \
    }                                                                                     \
    asm volatile("s_waitcnt lgkmcnt(0)" ::: "memory");                                    \
    __builtin_amdgcn_sched_barrier(0);                                                    \
  } while (0)

  // prologue: slabs 0,1. B via f32-reg-cvt; A via gload_lds.
  LOAD_B32(0);
  stageA(0, 0);
  CVT_B(-1);  // vmcnt(2): drains loadB(0); writes buf 0
  LOAD_B32(1);
  stageA(1, 1);
  CVT_B(0);   // vmcnt(2): drains gloadA(0)+loadB(1), leaves gloadA(1); writes buf 1
  asm volatile("s_waitcnt lgkmcnt(0)" ::: "memory");
  __builtin_amdgcn_s_barrier();
#pragma unroll
  for (int nf = 0; nf < 4; ++nf)
    b0[nf] = *(const bf16x8*)((const char*)Bsl + FRAG_PH(wn * 64 + nf * 16 + l15));
#pragma unroll
  for (int mf = 0; mf < 8; ++mf)
    a0[mf] = *(const bf16x8*)((const char*)Asl + FRAG_PH(wm * 128 + mf * 16 + l15));
  asm volatile("s_waitcnt lgkmcnt(0)" ::: "memory");
  __builtin_amdgcn_sched_barrier(0);

  // bodies: 0 (no cvt needed), 1..29 uniform, 30 (drain), tail 31
  BODY(a0, a1, b0, b1, 0, 0, 1, 6);
  for (int T = 1; T < 29; T += 2) {
    BODY(a1, a0, b1, b0, T, 1, 1, 6);
    BODY(a0, a1, b0, b1, T + 1, 1, 1, 6);
  }
  BODY(a1, a0, b1, b0, 29, 1, 1, 6);  // computes 29, stages slab 31
  BODY(a0, a1, b0, b1, 30, 1, 0, 0);  // computes 30, cvt+write B31, drain A31
  // tail: slab 31, registers only
  __builtin_amdgcn_s_setprio(1);
#pragma unroll
  for (int mf = 0; mf < 8; ++mf)
#pragma unroll
    for (int nf = 0; nf < 4; ++nf)
      acc[mf][nf] = __builtin_amdgcn_mfma_f32_16x16x32_bf16(a1[mf], b1[nf], acc[mf][nf], 0, 0, 0);
  __builtin_amdgcn_s_setprio(0);
#undef BODY
#undef CVT_B
#undef LOAD_B32
#undef FRAG_PH

  // ---- fused rule-aggregation epilogue (per-mf to bound register pressure) ----
  const int h = bn >> 11;                          // 2048 cols per head
  const int dbase = ((bn & 2047) + wn * 64) >> 5;  // even
#pragma unroll
  for (int mf = 0; mf < 8; ++mf) {
    int gm0 = bm + wm * 128 + mf * 16 + l4 * 4;
    float red[4][2];
#pragma unroll
    for (int q = 0; q < 4; ++q) { red[q][0] = 0.f; red[q][1] = 0.f; }
#pragma unroll
    for (int nf = 0; nf < 4; ++nf) {
      int col = bn + wn * 64 + nf * 16 + l15;
      float bval = bias[col];
      int r = (nf & 1) * 16 + l15;
      int g = nf >> 1;
#pragma unroll
      for (int q = 0; q < 4; ++q) {
        float w = attn[(size_t)(gm0 + q) * 512 + h * 32 + r];
        red[q][g] += (acc[mf][nf][q] + bval) * w;
      }
    }
#pragma unroll
    for (int q = 0; q < 4; ++q)
#pragma unroll
      for (int g = 0; g < 2; ++g) {
        float vv = red[q][g];
        for (int mask = 1; mask < 16; mask <<= 1) vv += __shfl_xor(vv, mask);
        red[q][g] = vv * scale;
      }
    if (l15 == 0) {
#pragma unroll
      for (int q = 0; q < 4; ++q) {
        int m = gm0 + q;
        int bb = m >> 10, s = m & 1023;
        size_t base = (((size_t)(bb * 16 + h)) * 1024 + s) * 64;
        unsigned lo = f32_to_bf16_rne(red[q][0]);
        unsigned hi = f32_to_bf16_rne(red[q][1]);
        ((unsigned*)X)[(base + dbase) >> 1] = lo | (hi << 16);
      }
    }
  }
}

extern "C" void kernel_launch(void* const* d_in, const int* in_sizes, int n_in, void* d_out,
                              int out_size, void* d_ws, size_t ws_size, hipStream_t stream) {
  const float* query = (const float*)d_in[0];
  const float* value = (const float*)d_in[2];
  const float* rk = (const float*)d_in[3];
  const float* rw = (const float*)d_in[4];
  const float* Wq = (const float*)d_in[5];
  const float* bq = (const float*)d_in[6];
  const float* Wv = (const float*)d_in[7];
  const float* bv = (const float*)d_in[8];
  const float* Wo = (const float*)d_in[9];
  const float* bo = (const float*)d_in[10];
  float* out = (float*)d_out;

  const float scale = 0.125f;

  char* p = (char*)d_ws;
  unsigned short* Aq_b = (unsigned short*)p; p += (size_t)2097152 * 2;
  unsigned short* Av_b = (unsigned short*)p; p += (size_t)2097152 * 2;
  unsigned short* Wq_b = (unsigned short*)p; p += (size_t)1048576 * 2;
  unsigned short* Wo_b = (unsigned short*)p; p += (size_t)1048576 * 2;
  float* qf = (float*)p;   p += (size_t)2097152 * 4;
  float* attn = (float*)p; p += (size_t)1048576 * 4;
  unsigned short* X = (unsigned short*)p;

  // convert q, v, Wq, Wo only (786432 chunks of 8 floats)
  cvt_all<<<3072, 256, 0, stream>>>(query, value, Wq, Wo, Aq_b, Av_b, Wq_b, Wo_b);

  // GEMM1: qf = (query @ Wq^T + bq) * scale   (2048 x 1024), 512 blocks
  gemm_bt64<<<dim3(16, 32), 256, 0, stream>>>(Aq_b, Wq_b, bq, scale, 2048, 1024, 1024, qf);
  // fuzzy membership + softmax
  fuzzy2_k<<<dim3(16, 16), 256, 0, stream>>>(qf, rk, rw, attn);
  // GEMM2 fused (round-8 schedule; B staged from f32 Wv in-kernel; 256-VGPR cap)
  hipFuncSetAttribute((const void*)gemm2_k, hipFuncAttributeMaxDynamicSharedMemorySize, 131072);
  gemm2_k<<<1024, 512, 131072, stream>>>(Av_b, Wv, bv, scale, attn, X);
  // GEMM3: out = X @ Wo^T + bo
  gemm_bt64<<<dim3(16, 32), 256, 0, stream>>>(X, Wo_b, bo, 1.0f, 2048, 1024, 1024, out);
}

// Round 14
// 252.621 us; speedup vs baseline: 5.7366x; 1.0153x over previous
//
#include <hip/hip_runtime.h>
#include <hip/hip_bf16.h>
#include <cstdint>

typedef float f32x4 __attribute__((ext_vector_type(4)));
typedef short bf16x8 __attribute__((ext_vector_type(8)));

__device__ __forceinline__ unsigned short f32_to_bf16_rne(float f) {
  unsigned int u = __float_as_uint(f);
  return (unsigned short)((u + 0x7FFFu + ((u >> 16) & 1u)) >> 16);
}

#define GLOAD_LDS16(gptr, lptr)                                                             \
  __builtin_amdgcn_global_load_lds((const __attribute__((address_space(1))) unsigned int*)(gptr), \
                                   (__attribute__((address_space(3))) unsigned int*)(lptr), 16, 0, 0)

// ---------------- fused f32 -> bf16 for q, v, Wq, Wo (8 elems / thread) -------------------
// (Wv is not pre-converted: gemm2 stages it from f32 directly.)
__global__ __launch_bounds__(256) void cvt_all(const float* __restrict__ q,
                                               const float* __restrict__ v,
                                               const float* __restrict__ wq,
                                               const float* __restrict__ wo,
                                               unsigned short* __restrict__ qb,
                                               unsigned short* __restrict__ vb,
                                               unsigned short* __restrict__ wqb,
                                               unsigned short* __restrict__ wob) {
  int i = blockIdx.x * 256 + threadIdx.x;  // chunk of 8 floats
  const float* src;
  unsigned short* dst;
  int off;
  if (i < 262144)      { src = q;  dst = qb;  off = i; }
  else if (i < 524288) { src = v;  dst = vb;  off = i - 262144; }
  else if (i < 655360) { src = wq; dst = wqb; off = i - 524288; }
  else                 { src = wo; dst = wob; off = i - 655360; }
  const float4* s = (const float4*)src;
  float4 a = s[2 * off], b = s[2 * off + 1];
  uint4 o;
  o.x = (unsigned)f32_to_bf16_rne(a.x) | ((unsigned)f32_to_bf16_rne(a.y) << 16);
  o.y = (unsigned)f32_to_bf16_rne(a.z) | ((unsigned)f32_to_bf16_rne(a.w) << 16);
  o.z = (unsigned)f32_to_bf16_rne(b.x) | ((unsigned)f32_to_bf16_rne(b.y) << 16);
  o.w = (unsigned)f32_to_bf16_rne(b.z) | ((unsigned)f32_to_bf16_rne(b.w) << 16);
  ((uint4*)dst)[off] = o;
}

// ---------------- fuzzy membership + softmax: LDS-staged rules, one head per block --------
__global__ __launch_bounds__(256) void fuzzy2_k(const float* __restrict__ qf,
                                                const float* __restrict__ rk,
                                                const float* __restrict__ rw,
                                                float* __restrict__ attn) {
  __shared__ float lk[32][65];
  __shared__ float lc[32][65];
  const int tid = threadIdx.x;
  const int h = blockIdx.y;
  const int mbase = blockIdx.x * 128;

  for (int idx = tid; idx < 2048; idx += 256) {
    int r = idx >> 6, d = idx & 63;
    lk[r][d] = rk[(size_t)(h * 32 + r) * 64 + d];
    float w = rw[(size_t)(h * 32 + r) * 64 + d];
    lc[r][d] = 0.0078125f / (w * w);
  }
  __syncthreads();

  const int g = tid >> 5;
  const int r = tid & 31;
#pragma unroll 1
  for (int it = 0; it < 16; ++it) {
    int m = mbase + it * 8 + g;
    const float* qrow = qf + (size_t)m * 1024 + h * 64;
    float acc = 0.f;
#pragma unroll
    for (int d0 = 0; d0 < 64; d0 += 4) {
      float4 q4 = *(const float4*)(qrow + d0);
      const float* qp = (const float*)&q4;
#pragma unroll
      for (int j = 0; j < 4; ++j) {
        float diff = qp[j] - lk[r][d0 + j];
        acc += lc[r][d0 + j] * diff * diff;
      }
    }
    float z = -acc;
    float mx = z;
#pragma unroll
    for (int mask = 16; mask >= 1; mask >>= 1) mx = fmaxf(mx, __shfl_xor(mx, mask));
    float e = __expf(z - mx);
    float s = e;
#pragma unroll
    for (int mask = 16; mask >= 1; mask >>= 1) s += __shfl_xor(s, mask);
    attn[(size_t)m * 512 + h * 32 + r] = e / s;
  }
}

// ---------------- small bf16 GEMM (64x64 tile, 512 blocks, ~8/CU): C = (A@W^T+b)*scale ----
__global__ __launch_bounds__(256) void gemm_bt64(const unsigned short* __restrict__ A,
                                                 const unsigned short* __restrict__ W,
                                                 const float* __restrict__ bias, float scale,
                                                 int M, int N, int K, float* __restrict__ Cf) {
  constexpr int BK = 32;
  __shared__ unsigned short As[2][64 * BK];
  __shared__ unsigned short Bs[2][64 * BK];
  const int tid = threadIdx.x;
  const int wid = tid >> 6;
  const int lane = tid & 63;
  const int l15 = lane & 15;
  const int l4 = lane >> 4;
  const int bm = blockIdx.y * 64;
  const int bn = blockIdx.x * 64;
  const int wr = (wid >> 1) * 32;
  const int wc = (wid & 1) * 32;

  f32x4 acc[2][2];
#pragma unroll
  for (int i = 0; i < 2; ++i)
#pragma unroll
    for (int j = 0; j < 2; ++j) acc[i][j] = (f32x4){0.f, 0.f, 0.f, 0.f};

  const int nk = K / BK;
  auto stage = [&](int buf, int kt) {
    int c = tid;  // 256 chunks of 16B per 4KB tile
    int row = c >> 2, ch = c & 3;
    int sch = ch ^ ((row >> 1) & 3);
    GLOAD_LDS16(A + (size_t)(bm + row) * K + kt * BK + sch * 8, &As[buf][c * 8]);
    GLOAD_LDS16(W + (size_t)(bn + row) * K + kt * BK + sch * 8, &Bs[buf][c * 8]);
  };

  stage(0, 0);
  __syncthreads();

  for (int kt = 0; kt < nk; ++kt) {
    const int cur = kt & 1;
    if (kt + 1 < nk) stage(cur ^ 1, kt + 1);
    bf16x8 a[2], b[2];
#pragma unroll
    for (int mi = 0; mi < 2; ++mi) {
      int rl = wr + mi * 16 + l15;
      int ph = (rl * 64 + l4 * 16) ^ ((((unsigned)rl >> 1) & 3) << 4);
      a[mi] = *(const bf16x8*)((const char*)&As[cur][0] + ph);
    }
#pragma unroll
    for (int ni = 0; ni < 2; ++ni) {
      int rl = wc + ni * 16 + l15;
      int ph = (rl * 64 + l4 * 16) ^ ((((unsigned)rl >> 1) & 3) << 4);
      b[ni] = *(const bf16x8*)((const char*)&Bs[cur][0] + ph);
    }
#pragma unroll
    for (int mi = 0; mi < 2; ++mi)
#pragma unroll
      for (int ni = 0; ni < 2; ++ni)
        acc[mi][ni] = __builtin_amdgcn_mfma_f32_16x16x32_bf16(a[mi], b[ni], acc[mi][ni], 0, 0, 0);
    __syncthreads();
  }

#pragma unroll
  for (int mi = 0; mi < 2; ++mi) {
#pragma unroll
    for (int ni = 0; ni < 2; ++ni) {
      int gm = bm + wr + mi * 16 + l4 * 4;
      int gn = bn + wc + ni * 16 + l15;
      float bval = bias[gn];
#pragma unroll
      for (int q = 0; q < 4; ++q)
        Cf[(size_t)(gm + q) * N + gn] = (acc[mi][ni][q] + bval) * scale;
    }
  }
}

// ---------------- GEMM2: 256x256, BK=32, 4-buf, B staged from f32, b SINGLE-buffered ------
// A: value bf16 (2048 x 1024), W32: Wv f32 (32768 x 1024)
// X[b,h,s,d] = scale * sum_r attn[m,h,r] * (A[m,:]@W[h*2048+d*32+r,:] + bias)
// REGISTER BUDGET (the r12/r13 lesson): cap = 256 unified (2 waves/SIMD). acc = 128 AGPR;
// arch must stay <= ~128. r12's b0/b1 double-buffer (32) + g00..g11 (16) = 268 total ->
// spill (WRITE_SIZE 41MB, MfmaUtil 20%). Fix: b single-buffered (16), reloaded in-cluster
// at mf==7 after each b[nf]'s last use (round-6 WAR pattern). Peak ~252/256.
// Ledger per BODY(T) (unchanged from r12 audit):
//   entry queue: [loadB(T+1) x4, gloadA(T+1) x2]
//   CVT: vmcnt(2) drains loadB(T+1) -> cvt -> 2x ds_write_b128 into buf (T+1)&3
//        (old content = slab T-3, reads drained 4 barriers earlier)
//   issue loadB(T+2) x4 + gloadA(T+2) x2
//   vmcnt(6) drains gloadA(T+1); lgkmcnt(0) makes writes visible; barrier
//   cluster: 32 MFMA on slab T; aN[mf] reads after each mf-group; b[nf] reloads at mf==7
__global__ __launch_bounds__(512, 2) void gemm2_k(const unsigned short* __restrict__ A,
                                                  const float* __restrict__ W32,
                                                  const float* __restrict__ bias, float scale,
                                                  const float* __restrict__ attn,
                                                  unsigned short* __restrict__ X) {
  constexpr int K = 1024, BK = 32;
  extern __shared__ unsigned short lds[];  // A: 4 x 8192, B: 4 x 8192 ushorts = 128 KB
  unsigned short* Asl = lds;
  unsigned short* Bsl = lds + 4 * 8192;
  const int tid = threadIdx.x;
  const int wid = tid >> 6, lane = tid & 63;
  const int l15 = lane & 15, l4 = lane >> 4;
  const int wm = wid >> 2, wn = wid & 3;  // wave tile 128x64

  // XCD-aware bijective swizzle: contiguous col-tile strip per XCD (B-panel L2 reuse)
  int orig = blockIdx.x;
  int swz = (orig & 7) * 128 + (orig >> 3);
  const int bm = (swz & 7) * 256, bn = (swz >> 3) * 256;

  auto stageA = [&](int buf, int kt) {
#pragma unroll
    for (int i = 0; i < 2; ++i) {
      int c = i * 512 + tid;  // 1024 chunks of 16B; slab = 256 rows x 4 chunks
      int row = c >> 2, ch = c & 3;
      int sch = ch ^ ((row >> 1) & 3);  // inverse swizzle on SOURCE (rule #21)
      GLOAD_LDS16(A + (size_t)(bm + row) * K + kt * BK + sch * 8, Asl + buf * 8192 + c * 8);
    }
  };

  f32x4 acc[8][4];
#pragma unroll
  for (int i = 0; i < 8; ++i)
#pragma unroll
    for (int j = 0; j < 4; ++j) acc[i][j] = (f32x4){0.f, 0.f, 0.f, 0.f};

  bf16x8 a0[8], a1[8], b[4];
  float4 g00, g01, g10, g11;  // staged f32 B chunks (live one body)

#define FRAG_PH(rl) (((rl) * 64 + l4 * 16) ^ ((((unsigned)rl >> 1) & 3) << 4))
#define PKR(lo, hi) ((unsigned)f32_to_bf16_rne(lo) | ((unsigned)f32_to_bf16_rne(hi) << 16))

  // issue the 4 f32 loads for B slab KT (queue position = old stageB)
#define LOAD_B32(KT)                                                                      \
  do {                                                                                    \
    int _c = tid, _row = _c >> 2, _sch = (_c & 3) ^ ((_row >> 1) & 3);                    \
    const float* _s0 = W32 + (size_t)(bn + _row) * 1024 + (KT) * 32 + _sch * 8;           \
    g00 = *(const float4*)_s0;                                                            \
    g01 = *(const float4*)(_s0 + 4);                                                      \
    _c = tid + 512; _row = _c >> 2; _sch = (_c & 3) ^ ((_row >> 1) & 3);                  \
    const float* _s1 = W32 + (size_t)(bn + _row) * 1024 + (KT) * 32 + _sch * 8;           \
    g10 = *(const float4*)_s1;                                                            \
    g11 = *(const float4*)(_s1 + 4);                                                      \
  } while (0)

  // finish B slab Tt+1: wait its loads (oldest 4 of queue), cvt, write to LDS
#define CVT_B(Tt)                                                                         \
  do {                                                                                    \
    asm volatile("s_waitcnt vmcnt(2)" ::: "memory");                                      \
    unsigned short* _dst = Bsl + (((Tt) + 1) & 3) * 8192;                                 \
    uint4 _p0, _p1;                                                                       \
    _p0.x = PKR(g00.x, g00.y); _p0.y = PKR(g00.z, g00.w);                                 \
    _p0.z = PKR(g01.x, g01.y); _p0.w = PKR(g01.z, g01.w);                                 \
    _p1.x = PKR(g10.x, g10.y); _p1.y = PKR(g10.z, g10.w);                                 \
    _p1.z = PKR(g11.x, g11.y); _p1.w = PKR(g11.z, g11.w);                                 \
    *reinterpret_cast<uint4*>(_dst + tid * 8) = _p0;                                      \
    *reinterpret_cast<uint4*>(_dst + (tid + 512) * 8) = _p1;                              \
  } while (0)

  // BODY(T): compute slab T with (aC, b); b[nf] reloads slab T+1 at mf==7 (after last
  // use); aN[mf] reloads after each mf's 4 MFMAs.
#define BODY(aC, aN, Tt, HAS_CVT, DO_STAGE, WN)                                           \
  do {                                                                                    \
    if (HAS_CVT) CVT_B(Tt);                                                               \
    if (DO_STAGE) { LOAD_B32((Tt) + 2); stageA(((Tt) + 2) & 3, (Tt) + 2); }               \
    asm volatile("s_waitcnt vmcnt(" #WN ")" ::: "memory");                                \
    asm volatile("s_waitcnt lgkmcnt(0)" ::: "memory");                                    \
    __builtin_amdgcn_s_barrier();                                                         \
    {                                                                                     \
      const char* _ab = (const char*)(Asl + (((Tt) + 1) & 3) * 8192);                     \
      const char* _bb = (const char*)(Bsl + (((Tt) + 1) & 3) * 8192);                     \
      __builtin_amdgcn_s_setprio(1);                                                      \
      _Pragma("unroll") for (int mf = 0; mf < 8; ++mf) {                                  \
        _Pragma("unroll") for (int nf = 0; nf < 4; ++nf) {                                \
          acc[mf][nf] =                                                                   \
              __builtin_amdgcn_mfma_f32_16x16x32_bf16(aC[mf], b[nf], acc[mf][nf], 0, 0, 0); \
          if (mf == 7)                                                                    \
            b[nf] = *(const bf16x8*)(_bb + FRAG_PH(wn * 64 + nf * 16 + l15));             \
        }                                                                                 \
        aN[mf] = *(const bf16x8*)(_ab + FRAG_PH(wm * 128 + mf * 16 + l15));               \
      }                                                                                   \
      __builtin_amdgcn_s_setprio(0);                                                      \
    }                                                                                     \
    asm volatile("s_waitcnt lgkmcnt(0)" ::: "memory");                                    \
    __builtin_amdgcn_sched_barrier(0);                                                    \
  } while (0)

  // prologue: slabs 0,1. B via f32-reg-cvt; A via gload_lds.
  LOAD_B32(0);
  stageA(0, 0);
  CVT_B(-1);  // vmcnt(2): drains loadB(0); writes buf 0
  LOAD_B32(1);
  stageA(1, 1);
  CVT_B(0);   // vmcnt(2): drains gloadA(0)+loadB(1), leaves gloadA(1); writes buf 1
  asm volatile("s_waitcnt lgkmcnt(0)" ::: "memory");
  __builtin_amdgcn_s_barrier();
#pragma unroll
  for (int nf = 0; nf < 4; ++nf)
    b[nf] = *(const bf16x8*)((const char*)Bsl + FRAG_PH(wn * 64 + nf * 16 + l15));
#pragma unroll
  for (int mf = 0; mf < 8; ++mf)
    a0[mf] = *(const bf16x8*)((const char*)Asl + FRAG_PH(wm * 128 + mf * 16 + l15));
  asm volatile("s_waitcnt lgkmcnt(0)" ::: "memory");
  __builtin_amdgcn_sched_barrier(0);

  // bodies: 0 (B slab 1 already written in prologue), 1..29 uniform, 30 (drain), tail 31
  BODY(a0, a1, 0, 0, 1, 6);
  for (int T = 1; T < 29; T += 2) {
    BODY(a1, a0, T, 1, 1, 6);
    BODY(a0, a1, T + 1, 1, 1, 6);
  }
  BODY(a1, a0, 29, 1, 1, 6);  // computes 29, stages slab 31
  BODY(a0, a1, 30, 1, 0, 0);  // computes 30, cvt+write B31, drain A31; b <- slab-31 frags
  // tail: slab 31, registers only
  __builtin_amdgcn_s_setprio(1);
#pragma unroll
  for (int mf = 0; mf < 8; ++mf)
#pragma unroll
    for (int nf = 0; nf < 4; ++nf)
      acc[mf][nf] = __builtin_amdgcn_mfma_f32_16x16x32_bf16(a1[mf], b[nf], acc[mf][nf], 0, 0, 0);
  __builtin_amdgcn_s_setprio(0);
#undef BODY
#undef CVT_B
#undef LOAD_B32
#undef FRAG_PH

  // ---- fused rule-aggregation epilogue (per-mf to bound register pressure) ----
  const int h = bn >> 11;                          // 2048 cols per head
  const int dbase = ((bn & 2047) + wn * 64) >> 5;  // even
#pragma unroll
  for (int mf = 0; mf < 8; ++mf) {
    int gm0 = bm + wm * 128 + mf * 16 + l4 * 4;
    float red[4][2];
#pragma unroll
    for (int q = 0; q < 4; ++q) { red[q][0] = 0.f; red[q][1] = 0.f; }
#pragma unroll
    for (int nf = 0; nf < 4; ++nf) {
      int col = bn + wn * 64 + nf * 16 + l15;
      float bval = bias[col];
      int r = (nf & 1) * 16 + l15;
      int g = nf >> 1;
#pragma unroll
      for (int q = 0; q < 4; ++q) {
        float w = attn[(size_t)(gm0 + q) * 512 + h * 32 + r];
        red[q][g] += (acc[mf][nf][q] + bval) * w;
      }
    }
#pragma unroll
    for (int q = 0; q < 4; ++q)
#pragma unroll
      for (int g = 0; g < 2; ++g) {
        float vv = red[q][g];
        for (int mask = 1; mask < 16; mask <<= 1) vv += __shfl_xor(vv, mask);
        red[q][g] = vv * scale;
      }
    if (l15 == 0) {
#pragma unroll
      for (int q = 0; q < 4; ++q) {
        int m = gm0 + q;
        int bb = m >> 10, s = m & 1023;
        size_t base = (((size_t)(bb * 16 + h)) * 1024 + s) * 64;
        unsigned lo = f32_to_bf16_rne(red[q][0]);
        unsigned hi = f32_to_bf16_rne(red[q][1]);
        ((unsigned*)X)[(base + dbase) >> 1] = lo | (hi << 16);
      }
    }
  }
}

extern "C" void kernel_launch(void* const* d_in, const int* in_sizes, int n_in, void* d_out,
                              int out_size, void* d_ws, size_t ws_size, hipStream_t stream) {
  const float* query = (const float*)d_in[0];
  const float* value = (const float*)d_in[2];
  const float* rk = (const float*)d_in[3];
  const float* rw = (const float*)d_in[4];
  const float* Wq = (const float*)d_in[5];
  const float* bq = (const float*)d_in[6];
  const float* Wv = (const float*)d_in[7];
  const float* bv = (const float*)d_in[8];
  const float* Wo = (const float*)d_in[9];
  const float* bo = (const float*)d_in[10];
  float* out = (float*)d_out;

  const float scale = 0.125f;

  char* p = (char*)d_ws;
  unsigned short* Aq_b = (unsigned short*)p; p += (size_t)2097152 * 2;
  unsigned short* Av_b = (unsigned short*)p; p += (size_t)2097152 * 2;
  unsigned short* Wq_b = (unsigned short*)p; p += (size_t)1048576 * 2;
  unsigned short* Wo_b = (unsigned short*)p; p += (size_t)1048576 * 2;
  float* qf = (float*)p;   p += (size_t)2097152 * 4;
  float* attn = (float*)p; p += (size_t)1048576 * 4;
  unsigned short* X = (unsigned short*)p;

  // convert q, v, Wq, Wo only (786432 chunks of 8 floats)
  cvt_all<<<3072, 256, 0, stream>>>(query, value, Wq, Wo, Aq_b, Av_b, Wq_b, Wo_b);

  // GEMM1: qf = (query @ Wq^T + bq) * scale   (2048 x 1024), 512 blocks
  gemm_bt64<<<dim3(16, 32), 256, 0, stream>>>(Aq_b, Wq_b, bq, scale, 2048, 1024, 1024, qf);
  // fuzzy membership + softmax
  fuzzy2_k<<<dim3(16, 16), 256, 0, stream>>>(qf, rk, rw, attn);
  // GEMM2 fused (B staged from f32 Wv in-kernel; b single-buffered to fit 256-reg budget)
  hipFuncSetAttribute((const void*)gemm2_k, hipFuncAttributeMaxDynamicSharedMemorySize, 131072);
  gemm2_k<<<1024, 512, 131072, stream>>>(Av_b, Wv, bv, scale, attn, X);
  // GEMM3: out = X @ Wo^T + bo
  gemm_bt64<<<dim3(16, 32), 256, 0, stream>>>(X, Wo_b, bo, 1.0f, 2048, 1024, 1024, out);
}

// Round 15
// 233.801 us; speedup vs baseline: 6.1984x; 1.0805x over previous
//
#include <hip/hip_runtime.h>
#include <hip/hip_bf16.h>
#include <cstdint>

typedef float f32x4 __attribute__((ext_vector_type(4)));
typedef short bf16x8 __attribute__((ext_vector_type(8)));

__device__ __forceinline__ unsigned short f32_to_bf16_rne(float f) {
  unsigned int u = __float_as_uint(f);
  return (unsigned short)((u + 0x7FFFu + ((u >> 16) & 1u)) >> 16);
}

#define GLOAD_LDS16(gptr, lptr)                                                             \
  __builtin_amdgcn_global_load_lds((const __attribute__((address_space(1))) unsigned int*)(gptr), \
                                   (__attribute__((address_space(3))) unsigned int*)(lptr), 16, 0, 0)

// ---------------- fused f32 -> bf16 for all 5 operands (8 elems / thread) ----------------
__global__ __launch_bounds__(256) void cvt_all(const float* __restrict__ wv,
                                               const float* __restrict__ q,
                                               const float* __restrict__ v,
                                               const float* __restrict__ wq,
                                               const float* __restrict__ wo,
                                               unsigned short* __restrict__ wvb,
                                               unsigned short* __restrict__ qb,
                                               unsigned short* __restrict__ vb,
                                               unsigned short* __restrict__ wqb,
                                               unsigned short* __restrict__ wob) {
  int i = blockIdx.x * 256 + threadIdx.x;  // chunk of 8 floats
  const float* src;
  unsigned short* dst;
  int off;
  if (i < 4194304)      { src = wv; dst = wvb; off = i; }
  else if (i < 4456448) { src = q;  dst = qb;  off = i - 4194304; }
  else if (i < 4718592) { src = v;  dst = vb;  off = i - 4456448; }
  else if (i < 4849664) { src = wq; dst = wqb; off = i - 4718592; }
  else                  { src = wo; dst = wob; off = i - 4849664; }
  const float4* s = (const float4*)src;
  float4 a = s[2 * off], b = s[2 * off + 1];
  uint4 o;
  o.x = (unsigned)f32_to_bf16_rne(a.x) | ((unsigned)f32_to_bf16_rne(a.y) << 16);
  o.y = (unsigned)f32_to_bf16_rne(a.z) | ((unsigned)f32_to_bf16_rne(a.w) << 16);
  o.z = (unsigned)f32_to_bf16_rne(b.x) | ((unsigned)f32_to_bf16_rne(b.y) << 16);
  o.w = (unsigned)f32_to_bf16_rne(b.z) | ((unsigned)f32_to_bf16_rne(b.w) << 16);
  ((uint4*)dst)[off] = o;
}

// ---------------- fuzzy membership + softmax: LDS-staged rules, one head per block --------
__global__ __launch_bounds__(256) void fuzzy2_k(const float* __restrict__ qf,
                                                const float* __restrict__ rk,
                                                const float* __restrict__ rw,
                                                float* __restrict__ attn) {
  __shared__ float lk[32][65];
  __shared__ float lc[32][65];
  const int tid = threadIdx.x;
  const int h = blockIdx.y;
  const int mbase = blockIdx.x * 128;

  for (int idx = tid; idx < 2048; idx += 256) {
    int r = idx >> 6, d = idx & 63;
    lk[r][d] = rk[(size_t)(h * 32 + r) * 64 + d];
    float w = rw[(size_t)(h * 32 + r) * 64 + d];
    lc[r][d] = 0.0078125f / (w * w);
  }
  __syncthreads();

  const int g = tid >> 5;
  const int r = tid & 31;
#pragma unroll 1
  for (int it = 0; it < 16; ++it) {
    int m = mbase + it * 8 + g;
    const float* qrow = qf + (size_t)m * 1024 + h * 64;
    float acc = 0.f;
#pragma unroll
    for (int d0 = 0; d0 < 64; d0 += 4) {
      float4 q4 = *(const float4*)(qrow + d0);
      const float* qp = (const float*)&q4;
#pragma unroll
      for (int j = 0; j < 4; ++j) {
        float diff = qp[j] - lk[r][d0 + j];
        acc += lc[r][d0 + j] * diff * diff;
      }
    }
    float z = -acc;
    float mx = z;
#pragma unroll
    for (int mask = 16; mask >= 1; mask >>= 1) mx = fmaxf(mx, __shfl_xor(mx, mask));
    float e = __expf(z - mx);
    float s = e;
#pragma unroll
    for (int mask = 16; mask >= 1; mask >>= 1) s += __shfl_xor(s, mask);
    attn[(size_t)m * 512 + h * 32 + r] = e / s;
  }
}

// ---------------- small bf16 GEMM (64x64 tile, 512 blocks, ~8/CU): C = (A@W^T+b)*scale ----
__global__ __launch_bounds__(256) void gemm_bt64(const unsigned short* __restrict__ A,
                                                 const unsigned short* __restrict__ W,
                                                 const float* __restrict__ bias, float scale,
                                                 int M, int N, int K, float* __restrict__ Cf) {
  constexpr int BK = 32;
  __shared__ unsigned short As[2][64 * BK];
  __shared__ unsigned short Bs[2][64 * BK];
  const int tid = threadIdx.x;
  const int wid = tid >> 6;
  const int lane = tid & 63;
  const int l15 = lane & 15;
  const int l4 = lane >> 4;
  const int bm = blockIdx.y * 64;
  const int bn = blockIdx.x * 64;
  const int wr = (wid >> 1) * 32;
  const int wc = (wid & 1) * 32;

  f32x4 acc[2][2];
#pragma unroll
  for (int i = 0; i < 2; ++i)
#pragma unroll
    for (int j = 0; j < 2; ++j) acc[i][j] = (f32x4){0.f, 0.f, 0.f, 0.f};

  const int nk = K / BK;
  auto stage = [&](int buf, int kt) {
    int c = tid;  // 256 chunks of 16B per 4KB tile
    int row = c >> 2, ch = c & 3;
    int sch = ch ^ ((row >> 1) & 3);
    GLOAD_LDS16(A + (size_t)(bm + row) * K + kt * BK + sch * 8, &As[buf][c * 8]);
    GLOAD_LDS16(W + (size_t)(bn + row) * K + kt * BK + sch * 8, &Bs[buf][c * 8]);
  };

  stage(0, 0);
  __syncthreads();

  for (int kt = 0; kt < nk; ++kt) {
    const int cur = kt & 1;
    if (kt + 1 < nk) stage(cur ^ 1, kt + 1);
    bf16x8 a[2], b[2];
#pragma unroll
    for (int mi = 0; mi < 2; ++mi) {
      int rl = wr + mi * 16 + l15;
      int ph = (rl * 64 + l4 * 16) ^ ((((unsigned)rl >> 1) & 3) << 4);
      a[mi] = *(const bf16x8*)((const char*)&As[cur][0] + ph);
    }
#pragma unroll
    for (int ni = 0; ni < 2; ++ni) {
      int rl = wc + ni * 16 + l15;
      int ph = (rl * 64 + l4 * 16) ^ ((((unsigned)rl >> 1) & 3) << 4);
      b[ni] = *(const bf16x8*)((const char*)&Bs[cur][0] + ph);
    }
#pragma unroll
    for (int mi = 0; mi < 2; ++mi)
#pragma unroll
      for (int ni = 0; ni < 2; ++ni)
        acc[mi][ni] = __builtin_amdgcn_mfma_f32_16x16x32_bf16(a[mi], b[ni], acc[mi][ni], 0, 0, 0);
    __syncthreads();
  }

#pragma unroll
  for (int mi = 0; mi < 2; ++mi) {
#pragma unroll
    for (int ni = 0; ni < 2; ++ni) {
      int gm = bm + wr + mi * 16 + l4 * 4;
      int gn = bn + wc + ni * 16 + l15;
      float bval = bias[gn];
#pragma unroll
      for (int q = 0; q < 4; ++q)
        Cf[(size_t)(gm + q) * N + gn] = (acc[mi][ni][q] + bval) * scale;
    }
  }
}

// ---------------- GEMM2: 256x256 tile, BK=32, 4-buf, dbl-buffered frags, fused agg --------
// A: value bf16 (2048 x 1024), W: Wv bf16 (32768 x 1024)
// X[b,h,s,d] = scale * sum_r attn[m,h,r] * (A[m,:]@W[h*2048+d*32+r,:] + bias)
// ROUND-8 CONFIG (best measured: 139 us, 988 TF, MfmaUtil 44.7%, VGPR 124+128 AGPR =
// 252/256 budget). Register budget is exactly at the 2-waves/SIMD cap: r12-r14 proved any
// added live state (e.g. 16 f32 staging regs) spills and halves throughput. Do not add
// state to this kernel.
// vmcnt: 4 gload_lds per tile-stage (2A+2B). BODY(T) issues stage(T+2): queue =
// stage(T+1)[4] + stage(T+2)[4] -> vmcnt(4) waits exactly tile T+1.
__global__ __launch_bounds__(512) void gemm2_k(const unsigned short* __restrict__ A,
                                               const unsigned short* __restrict__ W,
                                               const float* __restrict__ bias, float scale,
                                               const float* __restrict__ attn,
                                               unsigned short* __restrict__ X) {
  constexpr int K = 1024, BK = 32;
  extern __shared__ unsigned short lds[];  // A: 4 x 8192, B: 4 x 8192 ushorts = 128 KB
  unsigned short* Asl = lds;
  unsigned short* Bsl = lds + 4 * 8192;
  const int tid = threadIdx.x;
  const int wid = tid >> 6, lane = tid & 63;
  const int l15 = lane & 15, l4 = lane >> 4;
  const int wm = wid >> 2, wn = wid & 3;  // wave tile 128x64

  // XCD-aware bijective swizzle: contiguous col-tile strip per XCD (B-panel L2 reuse)
  int orig = blockIdx.x;
  int swz = (orig & 7) * 128 + (orig >> 3);
  const int bm = (swz & 7) * 256, bn = (swz >> 3) * 256;

  auto stageA = [&](int buf, int kt) {
#pragma unroll
    for (int i = 0; i < 2; ++i) {
      int c = i * 512 + tid;  // 1024 chunks of 16B; tile = 256 rows x 4 chunks
      int row = c >> 2, ch = c & 3;
      int sch = ch ^ ((row >> 1) & 3);  // inverse swizzle on SOURCE (rule #21)
      GLOAD_LDS16(A + (size_t)(bm + row) * K + kt * BK + sch * 8, Asl + buf * 8192 + c * 8);
    }
  };
  auto stageB = [&](int buf, int kt) {
#pragma unroll
    for (int i = 0; i < 2; ++i) {
      int c = i * 512 + tid;
      int row = c >> 2, ch = c & 3;
      int sch = ch ^ ((row >> 1) & 3);
      GLOAD_LDS16(W + (size_t)(bn + row) * K + kt * BK + sch * 8, Bsl + buf * 8192 + c * 8);
    }
  };

  f32x4 acc[8][4];
#pragma unroll
  for (int i = 0; i < 8; ++i)
#pragma unroll
    for (int j = 0; j < 4; ++j) acc[i][j] = (f32x4){0.f, 0.f, 0.f, 0.f};

  bf16x8 a0[8], a1[8], b0[4], b1[4];

#define FRAG_PH(rl) (((rl) * 64 + l4 * 16) ^ ((((unsigned)(rl) >> 1) & 3) << 4))

  // BODY: compute tile Tt from (aC,bC); stage Tt+2; load tile Tt+1 frags into (aN,bN),
  // 12 reads distributed 2-per-group over MFMA groups 0..5.
#define BODY(aC, aN, bC, bN, Tt, DO_STAGE, WN)                                            \
  do {                                                                                    \
    if (DO_STAGE) { stageA(((Tt) + 2) & 3, (Tt) + 2); stageB(((Tt) + 2) & 3, (Tt) + 2); } \
    asm volatile("s_waitcnt vmcnt(" #WN ")" ::: "memory");                                \
    __builtin_amdgcn_s_barrier();                                                         \
    {                                                                                     \
      const char* _ab = (const char*)(Asl + (((Tt) + 1) & 3) * 8192);                     \
      const char* _bb = (const char*)(Bsl + (((Tt) + 1) & 3) * 8192);                     \
      __builtin_amdgcn_s_setprio(1);                                                      \
      _Pragma("unroll") for (int mf = 0; mf < 8; ++mf) {                                  \
        _Pragma("unroll") for (int nf = 0; nf < 4; ++nf)                                  \
          acc[mf][nf] =                                                                   \
              __builtin_amdgcn_mfma_f32_16x16x32_bf16(aC[mf], bC[nf], acc[mf][nf], 0, 0, 0); \
        if (mf < 4) {                                                                     \
          aN[mf] = *(const bf16x8*)(_ab + FRAG_PH(wm * 128 + mf * 16 + l15));             \
          bN[mf] = *(const bf16x8*)(_bb + FRAG_PH(wn * 64 + mf * 16 + l15));              \
        } else if (mf < 6) {                                                              \
          int i0 = 2 * mf - 4, i1 = 2 * mf - 3;                                           \
          aN[i0] = *(const bf16x8*)(_ab + FRAG_PH(wm * 128 + i0 * 16 + l15));             \
          aN[i1] = *(const bf16x8*)(_ab + FRAG_PH(wm * 128 + i1 * 16 + l15));             \
        }                                                                                 \
      }                                                                                   \
      __builtin_amdgcn_s_setprio(0);                                                      \
    }                                                                                     \
    asm volatile("s_waitcnt lgkmcnt(0)" ::: "memory");                                    \
    __builtin_amdgcn_sched_barrier(0);                                                    \
  } while (0)

  // prologue: stage tiles 0,1 (8 loads); vmcnt(4) -> tile 0 landed; load tile-0 frags
  stageA(0, 0); stageB(0, 0);
  stageA(1, 1); stageB(1, 1);
  asm volatile("s_waitcnt vmcnt(4)" ::: "memory");
  __builtin_amdgcn_s_barrier();
#pragma unroll
  for (int nf = 0; nf < 4; ++nf)
    b0[nf] = *(const bf16x8*)((const char*)Bsl + FRAG_PH(wn * 64 + nf * 16 + l15));
#pragma unroll
  for (int mf = 0; mf < 8; ++mf)
    a0[mf] = *(const bf16x8*)((const char*)Asl + FRAG_PH(wm * 128 + mf * 16 + l15));
  asm volatile("s_waitcnt lgkmcnt(0)" ::: "memory");
  __builtin_amdgcn_sched_barrier(0);

  // bodies 0..29 (stage reaches tile 31 at body 29)
  for (int T = 0; T < 30; T += 2) {
    BODY(a0, a1, b0, b1, T, 1, 4);
    BODY(a1, a0, b1, b0, (T + 1), 1, 4);
  }
  // body 30: no stage; drain stage(31); load tile-31 frags into (a1,b1)
  BODY(a0, a1, b0, b1, 30, 0, 0);
  // tail: tile 31, registers only
  __builtin_amdgcn_s_setprio(1);
#pragma unroll
  for (int mf = 0; mf < 8; ++mf)
#pragma unroll
    for (int nf = 0; nf < 4; ++nf)
      acc[mf][nf] = __builtin_amdgcn_mfma_f32_16x16x32_bf16(a1[mf], b1[nf], acc[mf][nf], 0, 0, 0);
  __builtin_amdgcn_s_setprio(0);
#undef BODY
#undef FRAG_PH

  // ---- fused rule-aggregation epilogue (per-mf to bound register pressure) ----
  const int h = bn >> 11;                          // 2048 cols per head
  const int dbase = ((bn & 2047) + wn * 64) >> 5;  // even
#pragma unroll
  for (int mf = 0; mf < 8; ++mf) {
    int gm0 = bm + wm * 128 + mf * 16 + l4 * 4;
    float red[4][2];
#pragma unroll
    for (int q = 0; q < 4; ++q) { red[q][0] = 0.f; red[q][1] = 0.f; }
#pragma unroll
    for (int nf = 0; nf < 4; ++nf) {
      int col = bn + wn * 64 + nf * 16 + l15;
      float bval = bias[col];
      int r = (nf & 1) * 16 + l15;
      int g = nf >> 1;
#pragma unroll
      for (int q = 0; q < 4; ++q) {
        float w = attn[(size_t)(gm0 + q) * 512 + h * 32 + r];
        red[q][g] += (acc[mf][nf][q] + bval) * w;
      }
    }
#pragma unroll
    for (int q = 0; q < 4; ++q)
#pragma unroll
      for (int g = 0; g < 2; ++g) {
        float vv = red[q][g];
        for (int mask = 1; mask < 16; mask <<= 1) vv += __shfl_xor(vv, mask);
        red[q][g] = vv * scale;
      }
    if (l15 == 0) {
#pragma unroll
      for (int q = 0; q < 4; ++q) {
        int m = gm0 + q;
        int bb = m >> 10, s = m & 1023;
        size_t base = (((size_t)(bb * 16 + h)) * 1024 + s) * 64;
        unsigned lo = f32_to_bf16_rne(red[q][0]);
        unsigned hi = f32_to_bf16_rne(red[q][1]);
        ((unsigned*)X)[(base + dbase) >> 1] = lo | (hi << 16);
      }
    }
  }
}

extern "C" void kernel_launch(void* const* d_in, const int* in_sizes, int n_in, void* d_out,
                              int out_size, void* d_ws, size_t ws_size, hipStream_t stream) {
  const float* query = (const float*)d_in[0];
  const float* value = (const float*)d_in[2];
  const float* rk = (const float*)d_in[3];
  const float* rw = (const float*)d_in[4];
  const float* Wq = (const float*)d_in[5];
  const float* bq = (const float*)d_in[6];
  const float* Wv = (const float*)d_in[7];
  const float* bv = (const float*)d_in[8];
  const float* Wo = (const float*)d_in[9];
  const float* bo = (const float*)d_in[10];
  float* out = (float*)d_out;

  const float scale = 0.125f;

  char* p = (char*)d_ws;
  unsigned short* Wv_b = (unsigned short*)p; p += (size_t)33554432 * 2;
  unsigned short* Aq_b = (unsigned short*)p; p += (size_t)2097152 * 2;
  unsigned short* Av_b = (unsigned short*)p; p += (size_t)2097152 * 2;
  unsigned short* Wq_b = (unsigned short*)p; p += (size_t)1048576 * 2;
  unsigned short* Wo_b = (unsigned short*)p; p += (size_t)1048576 * 2;
  float* qf = (float*)p;   p += (size_t)2097152 * 4;
  float* attn = (float*)p; p += (size_t)1048576 * 4;
  unsigned short* X = (unsigned short*)p;

  cvt_all<<<19456, 256, 0, stream>>>(Wv, query, value, Wq, Wo, Wv_b, Aq_b, Av_b, Wq_b, Wo_b);

  // GEMM1: qf = (query @ Wq^T + bq) * scale   (2048 x 1024), 512 blocks
  gemm_bt64<<<dim3(16, 32), 256, 0, stream>>>(Aq_b, Wq_b, bq, scale, 2048, 1024, 1024, qf);
  // fuzzy membership + softmax
  fuzzy2_k<<<dim3(16, 16), 256, 0, stream>>>(qf, rk, rw, attn);
  // GEMM2 fused (256^2, 4-buf, 128KB dynamic LDS, double-buffered fragments)
  hipFuncSetAttribute((const void*)gemm2_k, hipFuncAttributeMaxDynamicSharedMemorySize, 131072);
  gemm2_k<<<1024, 512, 131072, stream>>>(Av_b, Wv_b, bv, scale, attn, X);
  // GEMM3: out = X @ Wo^T + bo
  gemm_bt64<<<dim3(16, 32), 256, 0, stream>>>(X, Wo_b, bo, 1.0f, 2048, 1024, 1024, out);
}